// Round 4
// baseline (205.830 us; speedup 1.0000x reference)
//
#include <hip/hip_runtime.h>
#include <hip/hip_bf16.h>

#define N_NODES 4096
#define LOG2E 1.44269504088896340736f
#define JT 256                      // j-tile staged in LDS per block

typedef __attribute__((ext_vector_type(8))) short bf16x8;
typedef __attribute__((ext_vector_type(4))) short bf16x4;
typedef __attribute__((ext_vector_type(4))) float f32x4;

static __device__ __forceinline__ ushort f2bf(float x) {
    union { float f; unsigned u; } v; v.f = x;
    unsigned u = v.u;
    return (ushort)((u + 0x7FFFu + ((u >> 16) & 1u)) >> 16);   // RNE
}

// ---------------- mask pack: adj [4096][4096] f32 -> bits [4096][128] u32 ----
__global__ __launch_bounds__(256) void k_pack_mask(const float* __restrict__ adj,
                                                   unsigned* __restrict__ maskw) {
    int idx = blockIdx.x * 256 + threadIdx.x;          // 4096*128 words
    int row = idx >> 7, w = idx & 127;
    const float4* ap = (const float4*)(adj + (size_t)row * N_NODES + w * 32);
    unsigned bits = 0;
#pragma unroll
    for (int q = 0; q < 8; ++q) {
        float4 v = ap[q];
        bits |= (v.x > 0.f ? 1u : 0u) << (q * 4 + 0);
        bits |= (v.y > 0.f ? 1u : 0u) << (q * 4 + 1);
        bits |= (v.z > 0.f ? 1u : 0u) << (q * 4 + 2);
        bits |= (v.w > 0.f ? 1u : 0u) << (q * 4 + 3);
    }
    maskw[idx] = bits;
}

// ---------------- W [h][K][64] f32 -> Wt hi/lo bf16 [h][64][K] (K-major) -----
__global__ void k_prep_w(const float* __restrict__ W, ushort* __restrict__ Wh,
                         ushort* __restrict__ Wl, int kshift, int total) {
    int idx = blockIdx.x * 256 + threadIdx.x;
    if (idx >= total) return;
    int K = 1 << kshift;
    int n = idx & 63;
    int k = (idx >> 6) & (K - 1);
    int h = idx >> (6 + kshift);
    float v = W[idx];
    ushort hi = f2bf(v);
    union { unsigned u; float f; } hv; hv.u = ((unsigned)hi) << 16;
    ushort lo = f2bf(v - hv.f);
    size_t dst = ((size_t)h * 64 + n) * K + k;
    Wh[dst] = hi; Wl[dst] = lo;
}

// ---------------- H = X @ W (3-term split bf16 MFMA)
// writes Ht n-major [head][64][4096] bf16  +  fused f1/f2 row-dots ------------
__global__ __launch_bounds__(256) void k_gemm_h(const float* __restrict__ X,
        const ushort* __restrict__ Wh, const ushort* __restrict__ Wl,
        const float* __restrict__ a,
        ushort* __restrict__ Ht, float* __restrict__ f1c, float* __restrict__ f2c,
        int K) {
    int head = blockIdx.y;
    int t = threadIdx.x, wave = t >> 6, lane = t & 63;
    int c = lane & 15, g = lane >> 4;
    int i0 = blockIdx.x * 64 + wave * 16;
    const float* xrow = X + (size_t)(i0 + c) * K;
    f32x4 acc[4] = {};
    for (int k0 = 0; k0 < K; k0 += 32) {
        const float4* xp = (const float4*)(xrow + k0 + g * 8);
        float4 xa = xp[0], xb = xp[1];
        float xs[8] = {xa.x, xa.y, xa.z, xa.w, xb.x, xb.y, xb.z, xb.w};
        union { ushort s[8]; bf16x8 v; } ah, al;
#pragma unroll
        for (int e = 0; e < 8; ++e) {
            ushort hb = f2bf(xs[e]);
            ah.s[e] = hb;
            union { unsigned u; float f; } hv; hv.u = ((unsigned)hb) << 16;
            al.s[e] = f2bf(xs[e] - hv.f);
        }
#pragma unroll
        for (int nt = 0; nt < 4; ++nt) {
            size_t boff = ((size_t)head * 64 + nt * 16 + c) * K + k0 + g * 8;
            bf16x8 bh = *(const bf16x8*)(Wh + boff);
            bf16x8 bl = *(const bf16x8*)(Wl + boff);
            acc[nt] = __builtin_amdgcn_mfma_f32_16x16x32_bf16(ah.v, bh, acc[nt], 0, 0, 0);
            acc[nt] = __builtin_amdgcn_mfma_f32_16x16x32_bf16(al.v, bh, acc[nt], 0, 0, 0);
            acc[nt] = __builtin_amdgcn_mfma_f32_16x16x32_bf16(ah.v, bl, acc[nt], 0, 0, 0);
        }
    }
    // --- Ht n-major store: Ht[(head*64 + n)*4096 + i], 4 rows packed per store
#pragma unroll
    for (int nt = 0; nt < 4; ++nt) {
        union { ushort s[4]; bf16x4 v; } pk;
#pragma unroll
        for (int r = 0; r < 4; ++r) pk.s[r] = f2bf(acc[nt][r]);
        *(bf16x4*)(Ht + ((size_t)head * 64 + nt * 16 + c) * N_NODES + i0 + g * 4) = pk.v;
    }
    // --- fused f1/f2: row i = i0 + g*4 + r; reduce over c
    float a1v[4], a2v[4];
#pragma unroll
    for (int nt = 0; nt < 4; ++nt) {
        a1v[nt] = a[head * 128 + nt * 16 + c];
        a2v[nt] = a[head * 128 + 64 + nt * 16 + c];
    }
#pragma unroll
    for (int r = 0; r < 4; ++r) {
        float f1 = 0.f, f2 = 0.f;
#pragma unroll
        for (int nt = 0; nt < 4; ++nt) {
            f1 = __builtin_fmaf(acc[nt][r], a1v[nt], f1);
            f2 = __builtin_fmaf(acc[nt][r], a2v[nt], f2);
        }
#pragma unroll
        for (int o = 1; o < 16; o <<= 1) {
            f1 += __shfl_xor(f1, o);
            f2 += __shfl_xor(f2, o);
        }
        if (c == 0) {
            int i = i0 + g * 4 + r;
            f1c[head * N_NODES + i] = (f1 - 16.0f) * LOG2E;   // fold -M shift
            f2c[head * N_NODES + i] = f2 * LOG2E;
        }
    }
}

// ---------------- masked flash attention — LDS-staged, swizzled, pipelined ---
// Block = 4 waves; wave owns 16 i-rows. Per 256-j tile: stage Ht[64n][256j]
// bf16 into 32KB LDS (reg-staged, 8x gload16 + 8x ds_write_b128 per thread,
// XOR-swizzled chunk = logical ^ (n&7) on BOTH source index and read addr).
// Next tile's loads issue before compute (T14). Fixed shift M=16 in f1c.
// __launch_bounds__(256,4): 4 blocks/CU (LDS caps at 5 anyway) -> 128 VGPR
// budget so the stg[8] staging regs DON'T spill to scratch (R3: 52 VGPRs,
// 240 MB/dispatch scratch writeback, spill-bound).
__global__ __launch_bounds__(256, 4) void k_attn(const ushort* __restrict__ Ht,
        const float* __restrict__ f1c, const float* __restrict__ f2c,
        const unsigned* __restrict__ maskw,
        float* __restrict__ accP, float* __restrict__ Zp, int JS) {
    int rb = blockIdx.x, js = blockIdx.y, head = blockIdx.z;
    int t = threadIdx.x, wave = t >> 6, lane = t & 63;
    int c = lane & 15, g = lane >> 4, c7 = c & 7;
    int i0 = rb * 64 + wave * 16;
    int irow = i0 + c;
    int jcount = N_NODES / JS;
    int j0 = js * jcount;
    int ntiles = jcount / JT;
    const float F1 = f1c[head * N_NODES + irow];
    const float* f2p = f2c + (size_t)head * N_NODES + j0 + g * 8;
    const unsigned* mrow = maskw + (size_t)irow * 128 + (j0 >> 5);
    const float NC = -12.8f * LOG2E;            // leakyrelu neg branch const
    f32x4 acc[4] = {};
    float z = 0.f;

    __shared__ ushort Hs[64 * JT];              // 32 KB, swizzled chunks

    // staging geometry: round s covers rows n = s*8 + tn, chunk slot tc
    int tn = t >> 5, tc = t & 31;
    int sjc = tc ^ tn;                          // source logical chunk (n&7==tn)
    const ushort* sp = Ht + ((size_t)head * 64 + tn) * N_NODES + j0 + sjc * 8;
    unsigned wb = (unsigned)(tn * JT + tc * 8) * 2;   // LDS byte for round 0

    int4 stg[8];
#pragma unroll
    for (int s = 0; s < 8; ++s)
        stg[s] = *(const int4*)(sp + (size_t)s * 8 * N_NODES);
    sp += JT;

    for (int tile = 0; tile < ntiles; ++tile) {
        __syncthreads();                        // prev tile's reads done
#pragma unroll
        for (int s = 0; s < 8; ++s)
            *(int4*)((char*)Hs + wb + s * 8 * JT * 2) = stg[s];
        __syncthreads();
        if (tile + 1 < ntiles) {
#pragma unroll
            for (int s = 0; s < 8; ++s)
                stg[s] = *(const int4*)(sp + (size_t)s * 8 * N_NODES);
            sp += JT;
        }
#pragma unroll
        for (int itr = 0; itr < JT / 32; ++itr) {
            // B-frags: row r = nt*16+c, logical chunk itr*4+g, phys ^= c7
            unsigned cb = (unsigned)(((itr * 4 + g) ^ c7) << 4);
            bf16x8 b0 = *(const bf16x8*)((const char*)Hs + (c      ) * JT * 2 + cb);
            bf16x8 b1 = *(const bf16x8*)((const char*)Hs + (c + 16) * JT * 2 + cb);
            bf16x8 b2 = *(const bf16x8*)((const char*)Hs + (c + 32) * JT * 2 + cb);
            bf16x8 b3 = *(const bf16x8*)((const char*)Hs + (c + 48) * JT * 2 + cb);
            unsigned w = *mrow++;
            unsigned bits = (w >> (g * 8)) & 0xFFu;
            float4 fa = ((const float4*)f2p)[0];
            float4 fb = ((const float4*)f2p)[1];
            f2p += 32;
            float f2v[8] = {fa.x, fa.y, fa.z, fa.w, fb.x, fb.y, fb.z, fb.w};
            unsigned pu[8];
#pragma unroll
            for (int e = 0; e < 8; ++e) {
                float u = F1 + f2v[e];
                float tnn = __builtin_fmaf(0.2f, u, NC);
                float m = fmaxf(u, tnn);
                float p = __builtin_amdgcn_exp2f(m);
                p = ((bits >> e) & 1u) ? p : 0.f;
                union { float f; unsigned u; } pv; pv.f = p;
                pu[e] = pv.u;
            }
            union { unsigned w[4]; bf16x8 v; } pa;
#pragma unroll
            for (int q = 0; q < 4; ++q) {
                unsigned hi1 = pu[2 * q + 1] & 0xFFFF0000u;
                unsigned hi0 = pu[2 * q] & 0xFFFF0000u;
                pa.w[q] = hi1 | (hi0 >> 16);
                union { unsigned u; float f; } z0, z1;
                z0.u = hi0; z1.u = hi1;
                z += z0.f + z1.f;                // z from truncated p: bias cancels
            }
            acc[0] = __builtin_amdgcn_mfma_f32_16x16x32_bf16(pa.v, b0, acc[0], 0, 0, 0);
            acc[1] = __builtin_amdgcn_mfma_f32_16x16x32_bf16(pa.v, b1, acc[1], 0, 0, 0);
            acc[2] = __builtin_amdgcn_mfma_f32_16x16x32_bf16(pa.v, b2, acc[2], 0, 0, 0);
            acc[3] = __builtin_amdgcn_mfma_f32_16x16x32_bf16(pa.v, b3, acc[3], 0, 0, 0);
        }
    }
    z += __shfl_xor(z, 16);
    z += __shfl_xor(z, 32);
    int slice = head * JS + js;
    if (g == 0) Zp[(size_t)slice * N_NODES + irow] = z;
    float* ap = accP + ((size_t)slice * N_NODES + i0) * 64;
#pragma unroll
    for (int nt = 0; nt < 4; ++nt)
#pragma unroll
        for (int r = 0; r < 4; ++r)
            ap[(g * 4 + r) * 64 + nt * 16 + c] = acc[nt][r];
}

// ---------------- combine partials -------------------------------------------
__global__ __launch_bounds__(256) void k_combine1(const float* __restrict__ accP,
        const float* __restrict__ Zp, float* __restrict__ x2, int JS) {
    int idx = blockIdx.x * 256 + threadIdx.x;    // 8*4096*64
    int n = idx & 63, i = (idx >> 6) & 4095, h = idx >> 18;
    float s = 0.f, z = 0.f;
    for (int j = 0; j < JS; ++j) {
        int sl = h * JS + j;
        s += accP[((size_t)sl * N_NODES + i) * 64 + n];
        z += Zp[(size_t)sl * N_NODES + i];
    }
    float v = s / z;
    v = v > 0.f ? v : (__builtin_amdgcn_exp2f(v * LOG2E) - 1.f);   // elu
    x2[(size_t)i * 512 + h * 64 + n] = v;
}

__global__ __launch_bounds__(256) void k_combine2(const float* __restrict__ accP,
        const float* __restrict__ Zp, float* __restrict__ out, int JS) {
    int idx = blockIdx.x * 256 + threadIdx.x;    // 4096*64
    int n = idx & 63, i = idx >> 6;
    float s = 0.f, z = 0.f;
    for (int j = 0; j < JS; ++j) {
        s += accP[((size_t)j * N_NODES + i) * 64 + n];
        z += Zp[(size_t)j * N_NODES + i];
    }
    out[idx] = s / z;
}

extern "C" void kernel_launch(void* const* d_in, const int* in_sizes, int n_in,
                              void* d_out, int out_size, void* d_ws, size_t ws_size,
                              hipStream_t stream) {
    const float* features = (const float*)d_in[0];
    const float* adj      = (const float*)d_in[1];
    const float* W_heads  = (const float*)d_in[2];
    const float* a_heads  = (const float*)d_in[3];
    const float* W_out    = (const float*)d_in[4];
    const float* a_out    = (const float*)d_in[5];
    float* out = (float*)d_out;

    // fixed (non-slice) buffers ≈ 16.2 MB; per-slice accP+Zp ≈ 1.07 MB
    size_t fixed = 16200000;
    size_t per_slice = (size_t)N_NODES * 64 * 4 + N_NODES * 4 + 512;
    int JS1 = 2, JS2 = 16;                       // 1024 blocks each (4/CU)
    if (ws_size < fixed + 16 * per_slice + 65536) { JS1 = 1; JS2 = 8; }
    int slices = (8 * JS1 > JS2) ? 8 * JS1 : JS2;

    char* ws = (char*)d_ws;
    size_t off = 0;
    auto alloc = [&](size_t bytes) -> void* {
        void* p = ws + off; off = (off + bytes + 255) & ~(size_t)255; return p;
    };
    unsigned* maskw = (unsigned*)alloc((size_t)N_NODES * 128 * 4);
    ushort* Ht1 = (ushort*)alloc((size_t)8 * 64 * N_NODES * 2);   // n-major
    ushort* Ht2 = (ushort*)alloc((size_t)64 * N_NODES * 2);
    float* f1c1 = (float*)alloc((size_t)8 * N_NODES * 4);
    float* f2c1 = (float*)alloc((size_t)8 * N_NODES * 4);
    float* f1c2 = (float*)alloc((size_t)N_NODES * 4);
    float* f2c2 = (float*)alloc((size_t)N_NODES * 4);
    ushort* Wh1 = (ushort*)alloc((size_t)8 * 64 * 256 * 2);
    ushort* Wl1 = (ushort*)alloc((size_t)8 * 64 * 256 * 2);
    ushort* Wh2 = (ushort*)alloc((size_t)64 * 512 * 2);
    ushort* Wl2 = (ushort*)alloc((size_t)64 * 512 * 2);
    float* x2   = (float*)alloc((size_t)N_NODES * 512 * 4);
    float* accP = (float*)alloc((size_t)slices * N_NODES * 64 * 4);
    float* Zp   = (float*)alloc((size_t)slices * N_NODES * 4);

    hipLaunchKernelGGL(k_pack_mask, dim3(N_NODES * 128 / 256), dim3(256), 0, stream, adj, maskw);
    hipLaunchKernelGGL(k_prep_w, dim3((8 * 256 * 64 + 255) / 256), dim3(256), 0, stream,
                       W_heads, Wh1, Wl1, 8, 8 * 256 * 64);
    hipLaunchKernelGGL(k_prep_w, dim3((512 * 64 + 255) / 256), dim3(256), 0, stream,
                       W_out, Wh2, Wl2, 9, 512 * 64);
    // layer 1
    hipLaunchKernelGGL(k_gemm_h, dim3(64, 8), dim3(256), 0, stream,
                       features, Wh1, Wl1, a_heads, Ht1, f1c1, f2c1, 256);
    hipLaunchKernelGGL(k_attn, dim3(64, JS1, 8), dim3(256), 0, stream,
                       Ht1, f1c1, f2c1, maskw, accP, Zp, JS1);
    hipLaunchKernelGGL(k_combine1, dim3(8 * N_NODES * 64 / 256), dim3(256), 0, stream,
                       accP, Zp, x2, JS1);
    // layer 2
    hipLaunchKernelGGL(k_gemm_h, dim3(64, 1), dim3(256), 0, stream,
                       x2, Wh2, Wl2, a_out, Ht2, f1c2, f2c2, 512);
    hipLaunchKernelGGL(k_attn, dim3(64, JS2, 1), dim3(256), 0, stream,
                       Ht2, f1c2, f2c2, maskw, accP, Zp, JS2);
    hipLaunchKernelGGL(k_combine2, dim3(N_NODES * 64 / 256), dim3(256), 0, stream,
                       accP, Zp, out, JS2);
}

// Round 5
// 150.416 us; speedup vs baseline: 1.3684x; 1.3684x over previous
//
#include <hip/hip_runtime.h>
#include <hip/hip_bf16.h>

#define N_NODES 4096
#define LOG2E 1.44269504088896340736f
#define JT 128                      // j-tile staged in LDS per block (dbuf)

typedef __attribute__((ext_vector_type(8))) short bf16x8;
typedef __attribute__((ext_vector_type(4))) short bf16x4;
typedef __attribute__((ext_vector_type(4))) float f32x4;

static __device__ __forceinline__ ushort f2bf(float x) {
    union { float f; unsigned u; } v; v.f = x;
    unsigned u = v.u;
    return (ushort)((u + 0x7FFFu + ((u >> 16) & 1u)) >> 16);   // RNE
}

// ---------------- mask pack: adj [4096][4096] f32 -> bits [4096][128] u32 ----
__global__ __launch_bounds__(256) void k_pack_mask(const float* __restrict__ adj,
                                                   unsigned* __restrict__ maskw) {
    int idx = blockIdx.x * 256 + threadIdx.x;          // 4096*128 words
    int row = idx >> 7, w = idx & 127;
    const float4* ap = (const float4*)(adj + (size_t)row * N_NODES + w * 32);
    unsigned bits = 0;
#pragma unroll
    for (int q = 0; q < 8; ++q) {
        float4 v = ap[q];
        bits |= (v.x > 0.f ? 1u : 0u) << (q * 4 + 0);
        bits |= (v.y > 0.f ? 1u : 0u) << (q * 4 + 1);
        bits |= (v.z > 0.f ? 1u : 0u) << (q * 4 + 2);
        bits |= (v.w > 0.f ? 1u : 0u) << (q * 4 + 3);
    }
    maskw[idx] = bits;
}

// ---------------- W [h][K][64] f32 -> Wt hi/lo bf16 [h][64][K] (K-major) -----
__global__ void k_prep_w(const float* __restrict__ W, ushort* __restrict__ Wh,
                         ushort* __restrict__ Wl, int kshift, int total) {
    int idx = blockIdx.x * 256 + threadIdx.x;
    if (idx >= total) return;
    int K = 1 << kshift;
    int n = idx & 63;
    int k = (idx >> 6) & (K - 1);
    int h = idx >> (6 + kshift);
    float v = W[idx];
    ushort hi = f2bf(v);
    union { unsigned u; float f; } hv; hv.u = ((unsigned)hi) << 16;
    ushort lo = f2bf(v - hv.f);
    size_t dst = ((size_t)h * 64 + n) * K + k;
    Wh[dst] = hi; Wl[dst] = lo;
}

// ---------------- H = X @ W (3-term split bf16 MFMA)
// writes Ht n-major [head][64][4096] bf16  +  fused f1/f2 row-dots ------------
__global__ __launch_bounds__(256) void k_gemm_h(const float* __restrict__ X,
        const ushort* __restrict__ Wh, const ushort* __restrict__ Wl,
        const float* __restrict__ a,
        ushort* __restrict__ Ht, float* __restrict__ f1c, float* __restrict__ f2c,
        int K) {
    int head = blockIdx.y;
    int t = threadIdx.x, wave = t >> 6, lane = t & 63;
    int c = lane & 15, g = lane >> 4;
    int i0 = blockIdx.x * 64 + wave * 16;
    const float* xrow = X + (size_t)(i0 + c) * K;
    f32x4 acc[4] = {};
    for (int k0 = 0; k0 < K; k0 += 32) {
        const float4* xp = (const float4*)(xrow + k0 + g * 8);
        float4 xa = xp[0], xb = xp[1];
        float xs[8] = {xa.x, xa.y, xa.z, xa.w, xb.x, xb.y, xb.z, xb.w};
        union { ushort s[8]; bf16x8 v; } ah, al;
#pragma unroll
        for (int e = 0; e < 8; ++e) {
            ushort hb = f2bf(xs[e]);
            ah.s[e] = hb;
            union { unsigned u; float f; } hv; hv.u = ((unsigned)hb) << 16;
            al.s[e] = f2bf(xs[e] - hv.f);
        }
#pragma unroll
        for (int nt = 0; nt < 4; ++nt) {
            size_t boff = ((size_t)head * 64 + nt * 16 + c) * K + k0 + g * 8;
            bf16x8 bh = *(const bf16x8*)(Wh + boff);
            bf16x8 bl = *(const bf16x8*)(Wl + boff);
            acc[nt] = __builtin_amdgcn_mfma_f32_16x16x32_bf16(ah.v, bh, acc[nt], 0, 0, 0);
            acc[nt] = __builtin_amdgcn_mfma_f32_16x16x32_bf16(al.v, bh, acc[nt], 0, 0, 0);
            acc[nt] = __builtin_amdgcn_mfma_f32_16x16x32_bf16(ah.v, bl, acc[nt], 0, 0, 0);
        }
    }
    // --- Ht n-major store: Ht[(head*64 + n)*4096 + i], 4 rows packed per store
#pragma unroll
    for (int nt = 0; nt < 4; ++nt) {
        union { ushort s[4]; bf16x4 v; } pk;
#pragma unroll
        for (int r = 0; r < 4; ++r) pk.s[r] = f2bf(acc[nt][r]);
        *(bf16x4*)(Ht + ((size_t)head * 64 + nt * 16 + c) * N_NODES + i0 + g * 4) = pk.v;
    }
    // --- fused f1/f2: row i = i0 + g*4 + r; reduce over c
    float a1v[4], a2v[4];
#pragma unroll
    for (int nt = 0; nt < 4; ++nt) {
        a1v[nt] = a[head * 128 + nt * 16 + c];
        a2v[nt] = a[head * 128 + 64 + nt * 16 + c];
    }
#pragma unroll
    for (int r = 0; r < 4; ++r) {
        float f1 = 0.f, f2 = 0.f;
#pragma unroll
        for (int nt = 0; nt < 4; ++nt) {
            f1 = __builtin_fmaf(acc[nt][r], a1v[nt], f1);
            f2 = __builtin_fmaf(acc[nt][r], a2v[nt], f2);
        }
#pragma unroll
        for (int o = 1; o < 16; o <<= 1) {
            f1 += __shfl_xor(f1, o);
            f2 += __shfl_xor(f2, o);
        }
        if (c == 0) {
            int i = i0 + g * 4 + r;
            f1c[head * N_NODES + i] = (f1 - 16.0f) * LOG2E;   // fold -M shift
            f2c[head * N_NODES + i] = f2 * LOG2E;
        }
    }
}

// ---------------- masked flash attention — global_load_lds double-buffer -----
// Block = 4 waves; wave owns 16 i-rows. Per 128-j tile: 4 global_load_lds
// rounds per wave (16 B/lane, wave-uniform LDS base + lane*16 = linear dest;
// XOR swizzle chunk^(n&7) pre-applied on the GLOBAL source index, m173).
// T3 2-phase: issue next tile's loads, s_waitcnt vmcnt(4) (current tile's
// loads are the oldest outstanding -> can never under-wait), raw s_barrier,
// compute, s_barrier. No staging VGPRs -> nothing for the allocator to spill
// (R3/R4: stg[8] spill = 242 MB/dispatch scratch writes, spill-bound).
__global__ __launch_bounds__(256)
__attribute__((amdgpu_waves_per_eu(4, 5)))
void k_attn(const ushort* __restrict__ Ht,
        const float* __restrict__ f1c, const float* __restrict__ f2c,
        const unsigned* __restrict__ maskw,
        float* __restrict__ accP, float* __restrict__ Zp, int JS) {
    int rb = blockIdx.x, js = blockIdx.y, head = blockIdx.z;
    int t = threadIdx.x, wave = t >> 6, lane = t & 63;
    int c = lane & 15, g = lane >> 4, c7 = c & 7;
    int i0 = rb * 64 + wave * 16;
    int irow = i0 + c;
    int jcount = N_NODES / JS;
    int j0 = js * jcount;
    int ntiles = jcount / JT;
    const float F1 = f1c[head * N_NODES + irow];
    const float* f2p = f2c + (size_t)head * N_NODES + j0 + g * 8;
    const unsigned* mrow = maskw + (size_t)irow * 128 + (j0 >> 5);
    const float NC = -12.8f * LOG2E;            // leakyrelu neg branch const
    f32x4 acc[4] = {};
    float z = 0.f;

    __shared__ ushort Hs[2][64 * JT];           // 2 x 16 KB

    // staging geometry: round s (0..3) covers rows n = s*16 + wave*4 + (lane>>4);
    // lane writes LDS halfword  s*2048 + wave*512 + lane*8  (= uniform + lane*16B);
    // source chunk pre-swizzled: sjc = (lane&15) ^ (rowb&7)
    int rowb = wave * 4 + (lane >> 4);          // 0..15
    int sjc = (lane & 15) ^ (rowb & 7);
    const ushort* gsp[4];
#pragma unroll
    for (int s = 0; s < 4; ++s)
        gsp[s] = Ht + ((size_t)head * 64 + s * 16 + rowb) * N_NODES + j0 + sjc * 8;
    int lbase = wave * 512;                     // halfwords, wave-uniform

#pragma unroll
    for (int s = 0; s < 4; ++s)                 // prologue: tile 0 -> buf 0
        __builtin_amdgcn_global_load_lds((const unsigned*)(gsp[s]),
                                         (unsigned*)&Hs[0][s * 2048 + lbase], 16, 0, 0);
    int buf = 0;
    for (int tile = 0; tile < ntiles; ++tile) {
        if (tile + 1 < ntiles) {
            int go = (tile + 1) * JT;
#pragma unroll
            for (int s = 0; s < 4; ++s)
                __builtin_amdgcn_global_load_lds((const unsigned*)(gsp[s] + go),
                        (unsigned*)&Hs[buf ^ 1][s * 2048 + lbase], 16, 0, 0);
            asm volatile("s_waitcnt vmcnt(4)");  // current tile landed, next in flight
        } else {
            asm volatile("s_waitcnt vmcnt(0)");
        }
        __builtin_amdgcn_s_barrier();

        const char* hb = (const char*)&Hs[buf][0];
#pragma unroll
        for (int itr = 0; itr < JT / 32; ++itr) {
            unsigned cb = (unsigned)(((itr * 4 + g) ^ c7) << 4);
            bf16x8 b0 = *(const bf16x8*)(hb + (c      ) * (JT * 2) + cb);
            bf16x8 b1 = *(const bf16x8*)(hb + (c + 16) * (JT * 2) + cb);
            bf16x8 b2 = *(const bf16x8*)(hb + (c + 32) * (JT * 2) + cb);
            bf16x8 b3 = *(const bf16x8*)(hb + (c + 48) * (JT * 2) + cb);
            unsigned w = *mrow++;
            unsigned bits = (w >> (g * 8)) & 0xFFu;
            float4 fa = ((const float4*)f2p)[0];
            float4 fb = ((const float4*)f2p)[1];
            f2p += 32;
            float f2v[8] = {fa.x, fa.y, fa.z, fa.w, fb.x, fb.y, fb.z, fb.w};
            unsigned pu[8];
#pragma unroll
            for (int e = 0; e < 8; ++e) {
                float u = F1 + f2v[e];
                float tnn = __builtin_fmaf(0.2f, u, NC);
                float m = fmaxf(u, tnn);
                float p = __builtin_amdgcn_exp2f(m);
                p = ((bits >> e) & 1u) ? p : 0.f;
                union { float f; unsigned u; } pv; pv.f = p;
                pu[e] = pv.u;
            }
            union { unsigned w[4]; bf16x8 v; } pa;
#pragma unroll
            for (int q = 0; q < 4; ++q) {
                unsigned hi1 = pu[2 * q + 1] & 0xFFFF0000u;
                unsigned hi0 = pu[2 * q] & 0xFFFF0000u;
                pa.w[q] = hi1 | (hi0 >> 16);
                union { unsigned u; float f; } z0, z1;
                z0.u = hi0; z1.u = hi1;
                z += z0.f + z1.f;                // z from truncated p: bias cancels
            }
            acc[0] = __builtin_amdgcn_mfma_f32_16x16x32_bf16(pa.v, b0, acc[0], 0, 0, 0);
            acc[1] = __builtin_amdgcn_mfma_f32_16x16x32_bf16(pa.v, b1, acc[1], 0, 0, 0);
            acc[2] = __builtin_amdgcn_mfma_f32_16x16x32_bf16(pa.v, b2, acc[2], 0, 0, 0);
            acc[3] = __builtin_amdgcn_mfma_f32_16x16x32_bf16(pa.v, b3, acc[3], 0, 0, 0);
        }
        __builtin_amdgcn_s_barrier();            // all waves done reading buf
        buf ^= 1;
    }
    z += __shfl_xor(z, 16);
    z += __shfl_xor(z, 32);
    int slice = head * JS + js;
    if (g == 0) Zp[(size_t)slice * N_NODES + irow] = z;
    float* ap = accP + ((size_t)slice * N_NODES + i0) * 64;
#pragma unroll
    for (int nt = 0; nt < 4; ++nt)
#pragma unroll
        for (int r = 0; r < 4; ++r)
            ap[(g * 4 + r) * 64 + nt * 16 + c] = acc[nt][r];
}

// ---------------- combine partials -------------------------------------------
__global__ __launch_bounds__(256) void k_combine1(const float* __restrict__ accP,
        const float* __restrict__ Zp, float* __restrict__ x2, int JS) {
    int idx = blockIdx.x * 256 + threadIdx.x;    // 8*4096*64
    int n = idx & 63, i = (idx >> 6) & 4095, h = idx >> 18;
    float s = 0.f, z = 0.f;
    for (int j = 0; j < JS; ++j) {
        int sl = h * JS + j;
        s += accP[((size_t)sl * N_NODES + i) * 64 + n];
        z += Zp[(size_t)sl * N_NODES + i];
    }
    float v = s / z;
    v = v > 0.f ? v : (__builtin_amdgcn_exp2f(v * LOG2E) - 1.f);   // elu
    x2[(size_t)i * 512 + h * 64 + n] = v;
}

__global__ __launch_bounds__(256) void k_combine2(const float* __restrict__ accP,
        const float* __restrict__ Zp, float* __restrict__ out, int JS) {
    int idx = blockIdx.x * 256 + threadIdx.x;    // 4096*64
    int n = idx & 63, i = idx >> 6;
    float s = 0.f, z = 0.f;
    for (int j = 0; j < JS; ++j) {
        s += accP[((size_t)j * N_NODES + i) * 64 + n];
        z += Zp[(size_t)j * N_NODES + i];
    }
    out[idx] = s / z;
}

extern "C" void kernel_launch(void* const* d_in, const int* in_sizes, int n_in,
                              void* d_out, int out_size, void* d_ws, size_t ws_size,
                              hipStream_t stream) {
    const float* features = (const float*)d_in[0];
    const float* adj      = (const float*)d_in[1];
    const float* W_heads  = (const float*)d_in[2];
    const float* a_heads  = (const float*)d_in[3];
    const float* W_out    = (const float*)d_in[4];
    const float* a_out    = (const float*)d_in[5];
    float* out = (float*)d_out;

    // fixed (non-slice) buffers ≈ 16.2 MB; per-slice accP+Zp ≈ 1.07 MB
    size_t fixed = 16200000;
    size_t per_slice = (size_t)N_NODES * 64 * 4 + N_NODES * 4 + 512;
    int JS1 = 2, JS2 = 16;                       // 1024 blocks each (4/CU)
    if (ws_size < fixed + 16 * per_slice + 65536) { JS1 = 1; JS2 = 8; }
    int slices = (8 * JS1 > JS2) ? 8 * JS1 : JS2;

    char* ws = (char*)d_ws;
    size_t off = 0;
    auto alloc = [&](size_t bytes) -> void* {
        void* p = ws + off; off = (off + bytes + 255) & ~(size_t)255; return p;
    };
    unsigned* maskw = (unsigned*)alloc((size_t)N_NODES * 128 * 4);
    ushort* Ht1 = (ushort*)alloc((size_t)8 * 64 * N_NODES * 2);   // n-major
    ushort* Ht2 = (ushort*)alloc((size_t)64 * N_NODES * 2);
    float* f1c1 = (float*)alloc((size_t)8 * N_NODES * 4);
    float* f2c1 = (float*)alloc((size_t)8 * N_NODES * 4);
    float* f1c2 = (float*)alloc((size_t)N_NODES * 4);
    float* f2c2 = (float*)alloc((size_t)N_NODES * 4);
    ushort* Wh1 = (ushort*)alloc((size_t)8 * 64 * 256 * 2);
    ushort* Wl1 = (ushort*)alloc((size_t)8 * 64 * 256 * 2);
    ushort* Wh2 = (ushort*)alloc((size_t)64 * 512 * 2);
    ushort* Wl2 = (ushort*)alloc((size_t)64 * 512 * 2);
    float* x2   = (float*)alloc((size_t)N_NODES * 512 * 4);
    float* accP = (float*)alloc((size_t)slices * N_NODES * 64 * 4);
    float* Zp   = (float*)alloc((size_t)slices * N_NODES * 4);

    hipLaunchKernelGGL(k_pack_mask, dim3(N_NODES * 128 / 256), dim3(256), 0, stream, adj, maskw);
    hipLaunchKernelGGL(k_prep_w, dim3((8 * 256 * 64 + 255) / 256), dim3(256), 0, stream,
                       W_heads, Wh1, Wl1, 8, 8 * 256 * 64);
    hipLaunchKernelGGL(k_prep_w, dim3((512 * 64 + 255) / 256), dim3(256), 0, stream,
                       W_out, Wh2, Wl2, 9, 512 * 64);
    // layer 1
    hipLaunchKernelGGL(k_gemm_h, dim3(64, 8), dim3(256), 0, stream,
                       features, Wh1, Wl1, a_heads, Ht1, f1c1, f2c1, 256);
    hipLaunchKernelGGL(k_attn, dim3(64, JS1, 8), dim3(256), 0, stream,
                       Ht1, f1c1, f2c1, maskw, accP, Zp, JS1);
    hipLaunchKernelGGL(k_combine1, dim3(8 * N_NODES * 64 / 256), dim3(256), 0, stream,
                       accP, Zp, x2, JS1);
    // layer 2
    hipLaunchKernelGGL(k_gemm_h, dim3(64, 1), dim3(256), 0, stream,
                       x2, Wh2, Wl2, a_out, Ht2, f1c2, f2c2, 512);
    hipLaunchKernelGGL(k_attn, dim3(64, JS2, 1), dim3(256), 0, stream,
                       Ht2, f1c2, f2c2, maskw, accP, Zp, JS2);
    hipLaunchKernelGGL(k_combine2, dim3(N_NODES * 64 / 256), dim3(256), 0, stream,
                       accP, Zp, out, JS2);
}

// Round 6
// 149.391 us; speedup vs baseline: 1.3778x; 1.0069x over previous
//
#include <hip/hip_runtime.h>
#include <hip/hip_bf16.h>

#define N_NODES 4096
#define LOG2E 1.44269504088896340736f
#define JT 64                       // j-tile staged in LDS per block (dbuf)

typedef __attribute__((ext_vector_type(8))) short bf16x8;
typedef __attribute__((ext_vector_type(4))) short bf16x4;
typedef __attribute__((ext_vector_type(4))) float f32x4;
typedef __attribute__((ext_vector_type(16))) float f32x16;

static __device__ __forceinline__ ushort f2bf(float x) {
    union { float f; unsigned u; } v; v.f = x;
    unsigned u = v.u;
    return (ushort)((u + 0x7FFFu + ((u >> 16) & 1u)) >> 16);   // RNE
}

// ---------------- mask pack: adj [4096][4096] f32 -> bits [4096][128] u32 ----
__global__ __launch_bounds__(256) void k_pack_mask(const float* __restrict__ adj,
                                                   unsigned* __restrict__ maskw) {
    int idx = blockIdx.x * 256 + threadIdx.x;          // 4096*128 words
    int row = idx >> 7, w = idx & 127;
    const float4* ap = (const float4*)(adj + (size_t)row * N_NODES + w * 32);
    unsigned bits = 0;
#pragma unroll
    for (int q = 0; q < 8; ++q) {
        float4 v = ap[q];
        bits |= (v.x > 0.f ? 1u : 0u) << (q * 4 + 0);
        bits |= (v.y > 0.f ? 1u : 0u) << (q * 4 + 1);
        bits |= (v.z > 0.f ? 1u : 0u) << (q * 4 + 2);
        bits |= (v.w > 0.f ? 1u : 0u) << (q * 4 + 3);
    }
    maskw[idx] = bits;
}

// ---------------- W [h][K][64] f32 -> Wt hi/lo bf16 [h][64][K] (K-major) -----
__global__ void k_prep_w(const float* __restrict__ W, ushort* __restrict__ Wh,
                         ushort* __restrict__ Wl, int kshift, int total) {
    int idx = blockIdx.x * 256 + threadIdx.x;
    if (idx >= total) return;
    int K = 1 << kshift;
    int n = idx & 63;
    int k = (idx >> 6) & (K - 1);
    int h = idx >> (6 + kshift);
    float v = W[idx];
    ushort hi = f2bf(v);
    union { unsigned u; float f; } hv; hv.u = ((unsigned)hi) << 16;
    ushort lo = f2bf(v - hv.f);
    size_t dst = ((size_t)h * 64 + n) * K + k;
    Wh[dst] = hi; Wl[dst] = lo;
}

// ---------------- H = X @ W (3-term split bf16 MFMA)
// writes Ht n-major [head][64][4096] bf16  +  fused f1/f2 row-dots ------------
__global__ __launch_bounds__(256) void k_gemm_h(const float* __restrict__ X,
        const ushort* __restrict__ Wh, const ushort* __restrict__ Wl,
        const float* __restrict__ a,
        ushort* __restrict__ Ht, float* __restrict__ f1c, float* __restrict__ f2c,
        int K) {
    int head = blockIdx.y;
    int t = threadIdx.x, wave = t >> 6, lane = t & 63;
    int c = lane & 15, g = lane >> 4;
    int i0 = blockIdx.x * 64 + wave * 16;
    const float* xrow = X + (size_t)(i0 + c) * K;
    f32x4 acc[4] = {};
    for (int k0 = 0; k0 < K; k0 += 32) {
        const float4* xp = (const float4*)(xrow + k0 + g * 8);
        float4 xa = xp[0], xb = xp[1];
        float xs[8] = {xa.x, xa.y, xa.z, xa.w, xb.x, xb.y, xb.z, xb.w};
        union { ushort s[8]; bf16x8 v; } ah, al;
#pragma unroll
        for (int e = 0; e < 8; ++e) {
            ushort hb = f2bf(xs[e]);
            ah.s[e] = hb;
            union { unsigned u; float f; } hv; hv.u = ((unsigned)hb) << 16;
            al.s[e] = f2bf(xs[e] - hv.f);
        }
#pragma unroll
        for (int nt = 0; nt < 4; ++nt) {
            size_t boff = ((size_t)head * 64 + nt * 16 + c) * K + k0 + g * 8;
            bf16x8 bh = *(const bf16x8*)(Wh + boff);
            bf16x8 bl = *(const bf16x8*)(Wl + boff);
            acc[nt] = __builtin_amdgcn_mfma_f32_16x16x32_bf16(ah.v, bh, acc[nt], 0, 0, 0);
            acc[nt] = __builtin_amdgcn_mfma_f32_16x16x32_bf16(al.v, bh, acc[nt], 0, 0, 0);
            acc[nt] = __builtin_amdgcn_mfma_f32_16x16x32_bf16(ah.v, bl, acc[nt], 0, 0, 0);
        }
    }
    // --- Ht n-major store
#pragma unroll
    for (int nt = 0; nt < 4; ++nt) {
        union { ushort s[4]; bf16x4 v; } pk;
#pragma unroll
        for (int r = 0; r < 4; ++r) pk.s[r] = f2bf(acc[nt][r]);
        *(bf16x4*)(Ht + ((size_t)head * 64 + nt * 16 + c) * N_NODES + i0 + g * 4) = pk.v;
    }
    // --- fused f1/f2
    float a1v[4], a2v[4];
#pragma unroll
    for (int nt = 0; nt < 4; ++nt) {
        a1v[nt] = a[head * 128 + nt * 16 + c];
        a2v[nt] = a[head * 128 + 64 + nt * 16 + c];
    }
#pragma unroll
    for (int r = 0; r < 4; ++r) {
        float f1 = 0.f, f2 = 0.f;
#pragma unroll
        for (int nt = 0; nt < 4; ++nt) {
            f1 = __builtin_fmaf(acc[nt][r], a1v[nt], f1);
            f2 = __builtin_fmaf(acc[nt][r], a2v[nt], f2);
        }
#pragma unroll
        for (int o = 1; o < 16; o <<= 1) {
            f1 += __shfl_xor(f1, o);
            f2 += __shfl_xor(f2, o);
        }
        if (c == 0) {
            int i = i0 + g * 4 + r;
            f1c[head * N_NODES + i] = (f1 - 16.0f) * LOG2E;   // fold -M shift
            f2c[head * N_NODES + i] = f2 * LOG2E;
        }
    }
}

// ---------------- masked flash attention ------------------------------------
// Block = 4 waves x 32 i-rows = 128 rows; mfma 32x32x16 (B-frag feeds 2x rows
// -> halves LDS read traffic/score). ALL per-tile data (H tile, mask words,
// f2 values) co-staged into LDS via global_load_lds, so the compute loop has
// ZERO VMEM ops and the counted per-wave vmcnt waits are exact (no in-order
// retirement pollution, m135). XOR-swizzled H (both-sides, rule #21).
__global__ __launch_bounds__(256)
__attribute__((amdgpu_waves_per_eu(4, 8)))
void k_attn(const ushort* __restrict__ Ht,
        const float* __restrict__ f1c, const float* __restrict__ f2c,
        const unsigned* __restrict__ maskw,
        float* __restrict__ accP, float* __restrict__ Zp, int JS) {
    int rb = blockIdx.x, js = blockIdx.y, head = blockIdx.z;
    int t = threadIdx.x, wave = t >> 6, lane = t & 63;
    int r32 = lane & 31, half = lane >> 5;
    int i0b = rb * 128;
    int i0w = i0b + wave * 32;
    int irow = i0w + r32;
    int jcount = N_NODES / JS;
    int j0 = js * jcount;
    int ntiles = jcount / JT;
    const float F1 = f1c[head * N_NODES + irow];
    const float NC = -12.8f * LOG2E;            // leakyrelu neg branch const

    __shared__ ushort Hs[2][64 * JT];           // 2 x 8 KB, swizzled chunks
    __shared__ unsigned Ms[2][256];             // 2 x 1 KB: [128 rows][2 words]
    __shared__ float F2s[2][64];                // 2 x 256 B

    // H staging: round s covers rows s*32 + rowb; phys slot lane&7 holds
    // logical chunk (lane&7)^(rowb&7)  (inverse-swizzled global source)
    int rowb = wave * 8 + (lane >> 3);
    int sjc = (lane & 7) ^ (rowb & 7);
    const ushort* gspH[2];
#pragma unroll
    for (int s = 0; s < 2; ++s)
        gspH[s] = Ht + ((size_t)head * 64 + s * 32 + rowb) * N_NODES + j0 + sjc * 8;
    // mask staging (wave 0, 4 rounds): idx = s*64+lane -> row s*32+(lane>>1), word lane&1
    const unsigned* msrc[4];
#pragma unroll
    for (int s = 0; s < 4; ++s)
        msrc[s] = maskw + (size_t)(i0b + s * 32 + (lane >> 1)) * 128 + (j0 >> 5) + (lane & 1);
    // f2 staging (wave 1): 64 contiguous floats
    const float* fsrc = f2c + (size_t)head * N_NODES + j0 + lane;

    auto stage = [&](int b, int tile) {
        int go = tile * JT;
#pragma unroll
        for (int s = 0; s < 2; ++s)
            __builtin_amdgcn_global_load_lds((const unsigned*)(gspH[s] + go),
                    (unsigned*)&Hs[b][s * 2048 + wave * 512], 16, 0, 0);
        if (wave == 0) {
#pragma unroll
            for (int s = 0; s < 4; ++s)
                __builtin_amdgcn_global_load_lds((const unsigned*)(msrc[s] + tile * 2),
                        (unsigned*)&Ms[b][s * 64], 4, 0, 0);
        } else if (wave == 1) {
            __builtin_amdgcn_global_load_lds((const unsigned*)(fsrc + go),
                    (unsigned*)&F2s[b][0], 4, 0, 0);
        }
    };

    f32x16 acc0 = {}, acc1 = {};
    float z = 0.f;

    stage(0, 0);
    int buf = 0;
    for (int tile = 0; tile < ntiles; ++tile) {
        if (tile + 1 < ntiles) {
            stage(buf ^ 1, tile + 1);
            if (wave == 0)      asm volatile("s_waitcnt vmcnt(6)");
            else if (wave == 1) asm volatile("s_waitcnt vmcnt(3)");
            else                asm volatile("s_waitcnt vmcnt(2)");
        } else {
            asm volatile("s_waitcnt vmcnt(0)");
        }
        __builtin_amdgcn_s_barrier();

        const char* hb = (const char*)&Hs[buf][0];
#pragma unroll
        for (int itr = 0; itr < JT / 16; ++itr) {
            unsigned phys = (unsigned)(((itr * 2 + half) ^ (r32 & 7)) << 4);
            bf16x8 b0 = *(const bf16x8*)(hb + r32 * 128 + phys);
            bf16x8 b1 = *(const bf16x8*)(hb + (32 + r32) * 128 + phys);
            unsigned mword = Ms[buf][(wave * 32 + r32) * 2 + (itr >> 1)];
            unsigned bits = (mword >> ((itr & 1) * 16 + half * 8)) & 0xFFu;
            const float* fp = &F2s[buf][itr * 16 + half * 8];
            float4 fa = *(const float4*)fp;
            float4 fb = *(const float4*)(fp + 4);
            float f2v[8] = {fa.x, fa.y, fa.z, fa.w, fb.x, fb.y, fb.z, fb.w};
            float p[8];
#pragma unroll
            for (int e = 0; e < 8; ++e) {
                float u = F1 + f2v[e];
                float tn = __builtin_fmaf(0.2f, u, NC);
                float m = fmaxf(u, tn);
                float pe = __builtin_amdgcn_exp2f(m);
                pe = ((bits >> e) & 1u) ? pe : 0.f;
                z += pe;
                p[e] = pe;
            }
            union { unsigned w[4]; bf16x8 v; } pa;
#pragma unroll
            for (int q = 0; q < 4; ++q)
                asm("v_cvt_pk_bf16_f32 %0, %1, %2"
                    : "=v"(pa.w[q]) : "v"(p[2 * q]), "v"(p[2 * q + 1]));
            acc0 = __builtin_amdgcn_mfma_f32_32x32x16_bf16(pa.v, b0, acc0, 0, 0, 0);
            acc1 = __builtin_amdgcn_mfma_f32_32x32x16_bf16(pa.v, b1, acc1, 0, 0, 0);
        }
        __builtin_amdgcn_s_barrier();
        buf ^= 1;
    }
    z += __shfl_xor(z, 32);
    int slice = head * JS + js;
    if (half == 0) Zp[(size_t)slice * N_NODES + irow] = z;
    float* ap = accP + ((size_t)slice * N_NODES + i0w) * 64;
#pragma unroll
    for (int reg = 0; reg < 16; ++reg) {
        int drow = (reg & 3) + 8 * (reg >> 2) + 4 * half;
        ap[drow * 64 + r32] = acc0[reg];
        ap[drow * 64 + 32 + r32] = acc1[reg];
    }
}

// ---------------- combine partials -------------------------------------------
__global__ __launch_bounds__(256) void k_combine1(const float* __restrict__ accP,
        const float* __restrict__ Zp, float* __restrict__ x2, int JS) {
    int idx = blockIdx.x * 256 + threadIdx.x;    // 8*4096*64
    int n = idx & 63, i = (idx >> 6) & 4095, h = idx >> 18;
    float s = 0.f, z = 0.f;
    for (int j = 0; j < JS; ++j) {
        int sl = h * JS + j;
        s += accP[((size_t)sl * N_NODES + i) * 64 + n];
        z += Zp[(size_t)sl * N_NODES + i];
    }
    float v = s / z;
    v = v > 0.f ? v : (__builtin_amdgcn_exp2f(v * LOG2E) - 1.f);   // elu
    x2[(size_t)i * 512 + h * 64 + n] = v;
}

__global__ __launch_bounds__(256) void k_combine2(const float* __restrict__ accP,
        const float* __restrict__ Zp, float* __restrict__ out, int JS) {
    int idx = blockIdx.x * 256 + threadIdx.x;    // 4096*64
    int n = idx & 63, i = idx >> 6;
    float s = 0.f, z = 0.f;
    for (int j = 0; j < JS; ++j) {
        s += accP[((size_t)j * N_NODES + i) * 64 + n];
        z += Zp[(size_t)j * N_NODES + i];
    }
    out[idx] = s / z;
}

extern "C" void kernel_launch(void* const* d_in, const int* in_sizes, int n_in,
                              void* d_out, int out_size, void* d_ws, size_t ws_size,
                              hipStream_t stream) {
    const float* features = (const float*)d_in[0];
    const float* adj      = (const float*)d_in[1];
    const float* W_heads  = (const float*)d_in[2];
    const float* a_heads  = (const float*)d_in[3];
    const float* W_out    = (const float*)d_in[4];
    const float* a_out    = (const float*)d_in[5];
    float* out = (float*)d_out;

    // fixed buffers ~16.1 MB; per-slice accP+Zp ~1.07 MB
    int JS1, JS2;
    if (ws_size >= 51500000)      { JS1 = 4; JS2 = 32; }   // slices 32
    else if (ws_size >= 34500000) { JS1 = 2; JS2 = 16; }
    else                          { JS1 = 1; JS2 = 8;  }
    int slices = (8 * JS1 > JS2) ? 8 * JS1 : JS2;

    char* ws = (char*)d_ws;
    size_t off = 0;
    auto alloc = [&](size_t bytes) -> void* {
        void* p = ws + off; off = (off + bytes + 255) & ~(size_t)255; return p;
    };
    unsigned* maskw = (unsigned*)alloc((size_t)N_NODES * 128 * 4);
    ushort* Ht1 = (ushort*)alloc((size_t)8 * 64 * N_NODES * 2);   // n-major
    ushort* Ht2 = (ushort*)alloc((size_t)64 * N_NODES * 2);
    float* f1c1 = (float*)alloc((size_t)8 * N_NODES * 4);
    float* f2c1 = (float*)alloc((size_t)8 * N_NODES * 4);
    float* f1c2 = (float*)alloc((size_t)N_NODES * 4);
    float* f2c2 = (float*)alloc((size_t)N_NODES * 4);
    ushort* Wh1 = (ushort*)alloc((size_t)8 * 64 * 256 * 2);
    ushort* Wl1 = (ushort*)alloc((size_t)8 * 64 * 256 * 2);
    ushort* Wh2 = (ushort*)alloc((size_t)64 * 512 * 2);
    ushort* Wl2 = (ushort*)alloc((size_t)64 * 512 * 2);
    float* x2   = (float*)alloc((size_t)N_NODES * 512 * 4);
    float* accP = (float*)alloc((size_t)slices * N_NODES * 64 * 4);
    float* Zp   = (float*)alloc((size_t)slices * N_NODES * 4);

    hipLaunchKernelGGL(k_pack_mask, dim3(N_NODES * 128 / 256), dim3(256), 0, stream, adj, maskw);
    hipLaunchKernelGGL(k_prep_w, dim3((8 * 256 * 64 + 255) / 256), dim3(256), 0, stream,
                       W_heads, Wh1, Wl1, 8, 8 * 256 * 64);
    hipLaunchKernelGGL(k_prep_w, dim3((512 * 64 + 255) / 256), dim3(256), 0, stream,
                       W_out, Wh2, Wl2, 9, 512 * 64);
    // layer 1
    hipLaunchKernelGGL(k_gemm_h, dim3(64, 8), dim3(256), 0, stream,
                       features, Wh1, Wl1, a_heads, Ht1, f1c1, f2c1, 256);
    hipLaunchKernelGGL(k_attn, dim3(32, JS1, 8), dim3(256), 0, stream,
                       Ht1, f1c1, f2c1, maskw, accP, Zp, JS1);
    hipLaunchKernelGGL(k_combine1, dim3(8 * N_NODES * 64 / 256), dim3(256), 0, stream,
                       accP, Zp, x2, JS1);
    // layer 2
    hipLaunchKernelGGL(k_gemm_h, dim3(64, 1), dim3(256), 0, stream,
                       x2, Wh2, Wl2, a_out, Ht2, f1c2, f2c2, 512);
    hipLaunchKernelGGL(k_attn, dim3(32, JS2, 1), dim3(256), 0, stream,
                       Ht2, f1c2, f2c2, maskw, accP, Zp, JS2);
    hipLaunchKernelGGL(k_combine2, dim3(N_NODES * 64 / 256), dim3(256), 0, stream,
                       accP, Zp, out, JS2);
}

// Round 7
// 142.221 us; speedup vs baseline: 1.4473x; 1.0504x over previous
//
#include <hip/hip_runtime.h>
#include <hip/hip_bf16.h>

#define N_NODES 4096
#define LOG2E 1.44269504088896340736f
#define JT 64                       // j-tile staged in LDS per block (dbuf)

typedef __attribute__((ext_vector_type(8))) short bf16x8;
typedef __attribute__((ext_vector_type(4))) short bf16x4;
typedef __attribute__((ext_vector_type(4))) float f32x4;
typedef __attribute__((ext_vector_type(16))) float f32x16;

static __device__ __forceinline__ ushort f2bf(float x) {
    union { float f; unsigned u; } v; v.f = x;
    unsigned u = v.u;
    return (ushort)((u + 0x7FFFu + ((u >> 16) & 1u)) >> 16);   // RNE
}

// ---------------- mask pack: adj [4096][4096] f32 -> bits [4096][128] u32 ----
__global__ __launch_bounds__(256) void k_pack_mask(const float* __restrict__ adj,
                                                   unsigned* __restrict__ maskw) {
    int idx = blockIdx.x * 256 + threadIdx.x;          // 4096*128 words
    int row = idx >> 7, w = idx & 127;
    const float4* ap = (const float4*)(adj + (size_t)row * N_NODES + w * 32);
    unsigned bits = 0;
#pragma unroll
    for (int q = 0; q < 8; ++q) {
        float4 v = ap[q];
        bits |= (v.x > 0.f ? 1u : 0u) << (q * 4 + 0);
        bits |= (v.y > 0.f ? 1u : 0u) << (q * 4 + 1);
        bits |= (v.z > 0.f ? 1u : 0u) << (q * 4 + 2);
        bits |= (v.w > 0.f ? 1u : 0u) << (q * 4 + 3);
    }
    maskw[idx] = bits;
}

// ---------------- W [h][K][64] f32 -> Wt hi/lo bf16 [h][64][K] (K-major) -----
__global__ void k_prep_w(const float* __restrict__ W, ushort* __restrict__ Wh,
                         ushort* __restrict__ Wl, int kshift, int total) {
    int idx = blockIdx.x * 256 + threadIdx.x;
    if (idx >= total) return;
    int K = 1 << kshift;
    int n = idx & 63;
    int k = (idx >> 6) & (K - 1);
    int h = idx >> (6 + kshift);
    float v = W[idx];
    ushort hi = f2bf(v);
    union { unsigned u; float f; } hv; hv.u = ((unsigned)hi) << 16;
    ushort lo = f2bf(v - hv.f);
    size_t dst = ((size_t)h * 64 + n) * K + k;
    Wh[dst] = hi; Wl[dst] = lo;
}

// ---------------- H = X @ W (3-term split bf16 MFMA)
// writes Ht n-major [head][64][4096] bf16 + per-node softmax factors:
//   R = exp(-0.8 f1),  E2 = exp(f2),  G2 = exp(0.2 f2)
// so that p'_ij = max(E2_j, R_i*G2_j) = exp(leakyrelu(f1+f2) - f1)  (exact),
// and softmax(p')==softmax(e) since the exp(f1_i) row factor cancels. --------
__global__ __launch_bounds__(256) void k_gemm_h(const float* __restrict__ X,
        const ushort* __restrict__ Wh, const ushort* __restrict__ Wl,
        const float* __restrict__ a,
        ushort* __restrict__ Ht, float* __restrict__ Rc,
        float* __restrict__ E2c, float* __restrict__ G2c, int K) {
    int head = blockIdx.y;
    int t = threadIdx.x, wave = t >> 6, lane = t & 63;
    int c = lane & 15, g = lane >> 4;
    int i0 = blockIdx.x * 64 + wave * 16;
    const float* xrow = X + (size_t)(i0 + c) * K;
    f32x4 acc[4] = {};
    for (int k0 = 0; k0 < K; k0 += 32) {
        const float4* xp = (const float4*)(xrow + k0 + g * 8);
        float4 xa = xp[0], xb = xp[1];
        float xs[8] = {xa.x, xa.y, xa.z, xa.w, xb.x, xb.y, xb.z, xb.w};
        union { ushort s[8]; bf16x8 v; } ah, al;
#pragma unroll
        for (int e = 0; e < 8; ++e) {
            ushort hb = f2bf(xs[e]);
            ah.s[e] = hb;
            union { unsigned u; float f; } hv; hv.u = ((unsigned)hb) << 16;
            al.s[e] = f2bf(xs[e] - hv.f);
        }
#pragma unroll
        for (int nt = 0; nt < 4; ++nt) {
            size_t boff = ((size_t)head * 64 + nt * 16 + c) * K + k0 + g * 8;
            bf16x8 bh = *(const bf16x8*)(Wh + boff);
            bf16x8 bl = *(const bf16x8*)(Wl + boff);
            acc[nt] = __builtin_amdgcn_mfma_f32_16x16x32_bf16(ah.v, bh, acc[nt], 0, 0, 0);
            acc[nt] = __builtin_amdgcn_mfma_f32_16x16x32_bf16(al.v, bh, acc[nt], 0, 0, 0);
            acc[nt] = __builtin_amdgcn_mfma_f32_16x16x32_bf16(ah.v, bl, acc[nt], 0, 0, 0);
        }
    }
    // --- Ht n-major store
#pragma unroll
    for (int nt = 0; nt < 4; ++nt) {
        union { ushort s[4]; bf16x4 v; } pk;
#pragma unroll
        for (int r = 0; r < 4; ++r) pk.s[r] = f2bf(acc[nt][r]);
        *(bf16x4*)(Ht + ((size_t)head * 64 + nt * 16 + c) * N_NODES + i0 + g * 4) = pk.v;
    }
    // --- fused f1/f2 row-dots -> per-node exp factors
    float a1v[4], a2v[4];
#pragma unroll
    for (int nt = 0; nt < 4; ++nt) {
        a1v[nt] = a[head * 128 + nt * 16 + c];
        a2v[nt] = a[head * 128 + 64 + nt * 16 + c];
    }
#pragma unroll
    for (int r = 0; r < 4; ++r) {
        float f1 = 0.f, f2 = 0.f;
#pragma unroll
        for (int nt = 0; nt < 4; ++nt) {
            f1 = __builtin_fmaf(acc[nt][r], a1v[nt], f1);
            f2 = __builtin_fmaf(acc[nt][r], a2v[nt], f2);
        }
#pragma unroll
        for (int o = 1; o < 16; o <<= 1) {
            f1 += __shfl_xor(f1, o);
            f2 += __shfl_xor(f2, o);
        }
        if (c == 0) {
            int i = i0 + g * 4 + r;
            Rc [head * N_NODES + i] = __builtin_amdgcn_exp2f(-0.8f * LOG2E * f1);
            E2c[head * N_NODES + i] = __builtin_amdgcn_exp2f(        LOG2E * f2);
            G2c[head * N_NODES + i] = __builtin_amdgcn_exp2f( 0.2f * LOG2E * f2);
        }
    }
}

// ---------------- masked flash attention ------------------------------------
// Block = 4 waves x 32 i-rows = 128 rows; mfma 32x32x16. Scores via the
// factorized form p' = max(E2_j, R_i*G2_j): ZERO transcendentals per pair.
// All per-tile data (H, mask, E2, G2) co-staged via global_load_lds ->
// compute loop has no VMEM ops, per-wave counted vmcnt is exact (m135).
__global__ __launch_bounds__(256)
__attribute__((amdgpu_waves_per_eu(4, 8)))
void k_attn(const ushort* __restrict__ Ht,
        const float* __restrict__ Rc, const float* __restrict__ E2c,
        const float* __restrict__ G2c, const unsigned* __restrict__ maskw,
        float* __restrict__ accP, float* __restrict__ Zp, int JS) {
    int rb = blockIdx.x, js = blockIdx.y, head = blockIdx.z;
    int t = threadIdx.x, wave = t >> 6, lane = t & 63;
    int r32 = lane & 31, half = lane >> 5;
    int i0b = rb * 128;
    int i0w = i0b + wave * 32;
    int irow = i0w + r32;
    int jcount = N_NODES / JS;
    int j0 = js * jcount;
    int ntiles = jcount / JT;
    const float R = Rc[head * N_NODES + irow];

    __shared__ ushort Hs[2][64 * JT];           // 2 x 8 KB, swizzled chunks
    __shared__ unsigned Ms[2][256];             // 2 x 1 KB: [128 rows][2 words]
    __shared__ float E2s[2][64];                // 2 x 256 B
    __shared__ float G2s[2][64];                // 2 x 256 B

    // H staging: round s covers rows s*32 + rowb; phys slot lane&7 holds
    // logical chunk (lane&7)^(rowb&7)  (inverse-swizzled global source)
    int rowb = wave * 8 + (lane >> 3);
    int sjc = (lane & 7) ^ (rowb & 7);
    const ushort* gspH[2];
#pragma unroll
    for (int s = 0; s < 2; ++s)
        gspH[s] = Ht + ((size_t)head * 64 + s * 32 + rowb) * N_NODES + j0 + sjc * 8;
    // mask staging (wave 0): idx = s*64+lane -> row s*32+(lane>>1), word lane&1
    const unsigned* msrc[4];
#pragma unroll
    for (int s = 0; s < 4; ++s)
        msrc[s] = maskw + (size_t)(i0b + s * 32 + (lane >> 1)) * 128 + (j0 >> 5) + (lane & 1);
    const float* esrc = E2c + (size_t)head * N_NODES + j0 + lane;   // wave 1
    const float* gsrc = G2c + (size_t)head * N_NODES + j0 + lane;   // wave 2

    auto stage = [&](int b, int tile) {
        int go = tile * JT;
#pragma unroll
        for (int s = 0; s < 2; ++s)
            __builtin_amdgcn_global_load_lds((const unsigned*)(gspH[s] + go),
                    (unsigned*)&Hs[b][s * 2048 + wave * 512], 16, 0, 0);
        if (wave == 0) {
#pragma unroll
            for (int s = 0; s < 4; ++s)
                __builtin_amdgcn_global_load_lds((const unsigned*)(msrc[s] + tile * 2),
                        (unsigned*)&Ms[b][s * 64], 4, 0, 0);
        } else if (wave == 1) {
            __builtin_amdgcn_global_load_lds((const unsigned*)(esrc + go),
                    (unsigned*)&E2s[b][0], 4, 0, 0);
        } else if (wave == 2) {
            __builtin_amdgcn_global_load_lds((const unsigned*)(gsrc + go),
                    (unsigned*)&G2s[b][0], 4, 0, 0);
        }
    };

    f32x16 acc0 = {}, acc1 = {};
    float z = 0.f;

    stage(0, 0);
    int buf = 0;
    for (int tile = 0; tile < ntiles; ++tile) {
        if (tile + 1 < ntiles) {
            stage(buf ^ 1, tile + 1);
            if (wave == 0)      asm volatile("s_waitcnt vmcnt(6)");
            else if (wave == 1) asm volatile("s_waitcnt vmcnt(3)");
            else if (wave == 2) asm volatile("s_waitcnt vmcnt(3)");
            else                asm volatile("s_waitcnt vmcnt(2)");
        } else {
            asm volatile("s_waitcnt vmcnt(0)");
        }
        __builtin_amdgcn_s_barrier();

        const char* hb = (const char*)&Hs[buf][0];
#pragma unroll
        for (int itr = 0; itr < JT / 16; ++itr) {
            unsigned phys = (unsigned)(((itr * 2 + half) ^ (r32 & 7)) << 4);
            bf16x8 b0 = *(const bf16x8*)(hb + r32 * 128 + phys);
            bf16x8 b1 = *(const bf16x8*)(hb + (32 + r32) * 128 + phys);
            unsigned mword = Ms[buf][(wave * 32 + r32) * 2 + (itr >> 1)];
            unsigned bits = (mword >> ((itr & 1) * 16 + half * 8)) & 0xFFu;
            const float* ep = &E2s[buf][itr * 16 + half * 8];
            const float* gp = &G2s[buf][itr * 16 + half * 8];
            float4 ea = *(const float4*)ep, eb = *(const float4*)(ep + 4);
            float4 ga = *(const float4*)gp, gb = *(const float4*)(gp + 4);
            float ev[8] = {ea.x, ea.y, ea.z, ea.w, eb.x, eb.y, eb.z, eb.w};
            float gv[8] = {ga.x, ga.y, ga.z, ga.w, gb.x, gb.y, gb.z, gb.w};
            float p[8];
#pragma unroll
            for (int e = 0; e < 8; ++e) {
                float pe = fmaxf(ev[e], R * gv[e]);    // exp(lrelu(s)-f1), exact
                pe = ((bits >> e) & 1u) ? pe : 0.f;
                z += pe;
                p[e] = pe;
            }
            union { unsigned w[4]; bf16x8 v; } pa;
#pragma unroll
            for (int q = 0; q < 4; ++q)
                asm("v_cvt_pk_bf16_f32 %0, %1, %2"
                    : "=v"(pa.w[q]) : "v"(p[2 * q]), "v"(p[2 * q + 1]));
            acc0 = __builtin_amdgcn_mfma_f32_32x32x16_bf16(pa.v, b0, acc0, 0, 0, 0);
            acc1 = __builtin_amdgcn_mfma_f32_32x32x16_bf16(pa.v, b1, acc1, 0, 0, 0);
        }
        __builtin_amdgcn_s_barrier();
        buf ^= 1;
    }
    z += __shfl_xor(z, 32);
    int slice = head * JS + js;
    if (half == 0) Zp[(size_t)slice * N_NODES + irow] = z;
    float* ap = accP + ((size_t)slice * N_NODES + i0w) * 64;
#pragma unroll
    for (int reg = 0; reg < 16; ++reg) {
        int drow = (reg & 3) + 8 * (reg >> 2) + 4 * half;
        ap[drow * 64 + r32] = acc0[reg];
        ap[drow * 64 + 32 + r32] = acc1[reg];
    }
}

// ---------------- combine partials -------------------------------------------
__global__ __launch_bounds__(256) void k_combine1(const float* __restrict__ accP,
        const float* __restrict__ Zp, float* __restrict__ x2, int JS) {
    int idx = blockIdx.x * 256 + threadIdx.x;    // 8*4096*64
    int n = idx & 63, i = (idx >> 6) & 4095, h = idx >> 18;
    float s = 0.f, z = 0.f;
    for (int j = 0; j < JS; ++j) {
        int sl = h * JS + j;
        s += accP[((size_t)sl * N_NODES + i) * 64 + n];
        z += Zp[(size_t)sl * N_NODES + i];
    }
    float v = s / z;
    v = v > 0.f ? v : (__builtin_amdgcn_exp2f(v * LOG2E) - 1.f);   // elu
    x2[(size_t)i * 512 + h * 64 + n] = v;
}

__global__ __launch_bounds__(256) void k_combine2(const float* __restrict__ accP,
        const float* __restrict__ Zp, float* __restrict__ out, int JS) {
    int idx = blockIdx.x * 256 + threadIdx.x;    // 4096*64
    int n = idx & 63, i = idx >> 6;
    float s = 0.f, z = 0.f;
    for (int j = 0; j < JS; ++j) {
        s += accP[((size_t)j * N_NODES + i) * 64 + n];
        z += Zp[(size_t)j * N_NODES + i];
    }
    out[idx] = s / z;
}

extern "C" void kernel_launch(void* const* d_in, const int* in_sizes, int n_in,
                              void* d_out, int out_size, void* d_ws, size_t ws_size,
                              hipStream_t stream) {
    const float* features = (const float*)d_in[0];
    const float* adj      = (const float*)d_in[1];
    const float* W_heads  = (const float*)d_in[2];
    const float* a_heads  = (const float*)d_in[3];
    const float* W_out    = (const float*)d_in[4];
    const float* a_out    = (const float*)d_in[5];
    float* out = (float*)d_out;

    // fixed buffers ~16.3 MB; per-slice accP+Zp ~1.07 MB
    int JS1, JS2;
    if (ws_size >= 51700000)      { JS1 = 4; JS2 = 32; }   // slices 32
    else if (ws_size >= 34700000) { JS1 = 2; JS2 = 16; }
    else                          { JS1 = 1; JS2 = 8;  }
    int slices = (8 * JS1 > JS2) ? 8 * JS1 : JS2;

    char* ws = (char*)d_ws;
    size_t off = 0;
    auto alloc = [&](size_t bytes) -> void* {
        void* p = ws + off; off = (off + bytes + 255) & ~(size_t)255; return p;
    };
    unsigned* maskw = (unsigned*)alloc((size_t)N_NODES * 128 * 4);
    ushort* Ht1 = (ushort*)alloc((size_t)8 * 64 * N_NODES * 2);   // n-major
    ushort* Ht2 = (ushort*)alloc((size_t)64 * N_NODES * 2);
    float* Rc1  = (float*)alloc((size_t)8 * N_NODES * 4);
    float* E2c1 = (float*)alloc((size_t)8 * N_NODES * 4);
    float* G2c1 = (float*)alloc((size_t)8 * N_NODES * 4);
    float* Rc2  = (float*)alloc((size_t)N_NODES * 4);
    float* E2c2 = (float*)alloc((size_t)N_NODES * 4);
    float* G2c2 = (float*)alloc((size_t)N_NODES * 4);
    ushort* Wh1 = (ushort*)alloc((size_t)8 * 64 * 256 * 2);
    ushort* Wl1 = (ushort*)alloc((size_t)8 * 64 * 256 * 2);
    ushort* Wh2 = (ushort*)alloc((size_t)64 * 512 * 2);
    ushort* Wl2 = (ushort*)alloc((size_t)64 * 512 * 2);
    float* x2   = (float*)alloc((size_t)N_NODES * 512 * 4);
    float* accP = (float*)alloc((size_t)slices * N_NODES * 64 * 4);
    float* Zp   = (float*)alloc((size_t)slices * N_NODES * 4);

    hipLaunchKernelGGL(k_pack_mask, dim3(N_NODES * 128 / 256), dim3(256), 0, stream, adj, maskw);
    hipLaunchKernelGGL(k_prep_w, dim3((8 * 256 * 64 + 255) / 256), dim3(256), 0, stream,
                       W_heads, Wh1, Wl1, 8, 8 * 256 * 64);
    hipLaunchKernelGGL(k_prep_w, dim3((512 * 64 + 255) / 256), dim3(256), 0, stream,
                       W_out, Wh2, Wl2, 9, 512 * 64);
    // layer 1
    hipLaunchKernelGGL(k_gemm_h, dim3(64, 8), dim3(256), 0, stream,
                       features, Wh1, Wl1, a_heads, Ht1, Rc1, E2c1, G2c1, 256);
    hipLaunchKernelGGL(k_attn, dim3(32, JS1, 8), dim3(256), 0, stream,
                       Ht1, Rc1, E2c1, G2c1, maskw, accP, Zp, JS1);
    hipLaunchKernelGGL(k_combine1, dim3(8 * N_NODES * 64 / 256), dim3(256), 0, stream,
                       accP, Zp, x2, JS1);
    // layer 2
    hipLaunchKernelGGL(k_gemm_h, dim3(64, 1), dim3(256), 0, stream,
                       x2, Wh2, Wl2, a_out, Ht2, Rc2, E2c2, G2c2, 512);
    hipLaunchKernelGGL(k_attn, dim3(32, JS2, 1), dim3(256), 0, stream,
                       Ht2, Rc2, E2c2, G2c2, maskw, accP, Zp, JS2);
    hipLaunchKernelGGL(k_combine2, dim3(N_NODES * 64 / 256), dim3(256), 0, stream,
                       accP, Zp, out, JS2);
}

// Round 8
// 139.828 us; speedup vs baseline: 1.4720x; 1.0171x over previous
//
#include <hip/hip_runtime.h>
#include <hip/hip_bf16.h>

#define N_NODES 4096
#define LOG2E 1.44269504088896340736f
#define JT 128                      // j-tile staged in LDS per block (dbuf)

typedef __attribute__((ext_vector_type(8))) short bf16x8;
typedef __attribute__((ext_vector_type(4))) short bf16x4;
typedef __attribute__((ext_vector_type(4))) float f32x4;
typedef __attribute__((ext_vector_type(16))) float f32x16;

static __device__ __forceinline__ ushort f2bf(float x) {
    union { float f; unsigned u; } v; v.f = x;
    unsigned u = v.u;
    return (ushort)((u + 0x7FFFu + ((u >> 16) & 1u)) >> 16);   // RNE
}

// ---------------- mask pack: adj [4096][4096] f32 -> bits [4096][128] u32 ----
__global__ __launch_bounds__(256) void k_pack_mask(const float* __restrict__ adj,
                                                   unsigned* __restrict__ maskw) {
    int idx = blockIdx.x * 256 + threadIdx.x;          // 4096*128 words
    int row = idx >> 7, w = idx & 127;
    const float4* ap = (const float4*)(adj + (size_t)row * N_NODES + w * 32);
    unsigned bits = 0;
#pragma unroll
    for (int q = 0; q < 8; ++q) {
        float4 v = ap[q];
        bits |= (v.x > 0.f ? 1u : 0u) << (q * 4 + 0);
        bits |= (v.y > 0.f ? 1u : 0u) << (q * 4 + 1);
        bits |= (v.z > 0.f ? 1u : 0u) << (q * 4 + 2);
        bits |= (v.w > 0.f ? 1u : 0u) << (q * 4 + 3);
    }
    maskw[idx] = bits;
}

// ---------------- W [h][K][64] f32 -> Wt hi/lo bf16 [h][64][K] (K-major) -----
__global__ void k_prep_w(const float* __restrict__ W, ushort* __restrict__ Wh,
                         ushort* __restrict__ Wl, int kshift, int total) {
    int idx = blockIdx.x * 256 + threadIdx.x;
    if (idx >= total) return;
    int K = 1 << kshift;
    int n = idx & 63;
    int k = (idx >> 6) & (K - 1);
    int h = idx >> (6 + kshift);
    float v = W[idx];
    ushort hi = f2bf(v);
    union { unsigned u; float f; } hv; hv.u = ((unsigned)hi) << 16;
    ushort lo = f2bf(v - hv.f);
    size_t dst = ((size_t)h * 64 + n) * K + k;
    Wh[dst] = hi; Wl[dst] = lo;
}

// ---------------- H = X @ W (3-term split bf16 MFMA)
// Softmax factorization (exact): w_ij = G2_j * max(T_j, R_i) = exp(lrelu(f1+f2)-f1)
//   T = exp(0.8 f2), R = exp(-0.8 f1), G2 = exp(0.2 f2).
// G2 is folded INTO the staged Ht (bf16(acc*G2): same single rounding as before)
// and provided as bf16 (G2b) for the z-accumulating MFMA. -------------------
__global__ __launch_bounds__(256) void k_gemm_h(const float* __restrict__ X,
        const ushort* __restrict__ Wh, const ushort* __restrict__ Wl,
        const float* __restrict__ a,
        ushort* __restrict__ Ht, float* __restrict__ Rc,
        float* __restrict__ Tc, ushort* __restrict__ G2b, int K) {
    int head = blockIdx.y;
    int t = threadIdx.x, wave = t >> 6, lane = t & 63;
    int c = lane & 15, g = lane >> 4;
    int i0 = blockIdx.x * 64 + wave * 16;
    const float* xrow = X + (size_t)(i0 + c) * K;
    f32x4 acc[4] = {};
    for (int k0 = 0; k0 < K; k0 += 32) {
        const float4* xp = (const float4*)(xrow + k0 + g * 8);
        float4 xa = xp[0], xb = xp[1];
        float xs[8] = {xa.x, xa.y, xa.z, xa.w, xb.x, xb.y, xb.z, xb.w};
        union { ushort s[8]; bf16x8 v; } ah, al;
#pragma unroll
        for (int e = 0; e < 8; ++e) {
            ushort hb = f2bf(xs[e]);
            ah.s[e] = hb;
            union { unsigned u; float f; } hv; hv.u = ((unsigned)hb) << 16;
            al.s[e] = f2bf(xs[e] - hv.f);
        }
#pragma unroll
        for (int nt = 0; nt < 4; ++nt) {
            size_t boff = ((size_t)head * 64 + nt * 16 + c) * K + k0 + g * 8;
            bf16x8 bh = *(const bf16x8*)(Wh + boff);
            bf16x8 bl = *(const bf16x8*)(Wl + boff);
            acc[nt] = __builtin_amdgcn_mfma_f32_16x16x32_bf16(ah.v, bh, acc[nt], 0, 0, 0);
            acc[nt] = __builtin_amdgcn_mfma_f32_16x16x32_bf16(al.v, bh, acc[nt], 0, 0, 0);
            acc[nt] = __builtin_amdgcn_mfma_f32_16x16x32_bf16(ah.v, bl, acc[nt], 0, 0, 0);
        }
    }
    // --- fused f1/f2 row-dots -> per-node factors (before Ht store: need G2)
    float a1v[4], a2v[4];
#pragma unroll
    for (int nt = 0; nt < 4; ++nt) {
        a1v[nt] = a[head * 128 + nt * 16 + c];
        a2v[nt] = a[head * 128 + 64 + nt * 16 + c];
    }
    float G2f[4];
#pragma unroll
    for (int r = 0; r < 4; ++r) {
        float f1 = 0.f, f2 = 0.f;
#pragma unroll
        for (int nt = 0; nt < 4; ++nt) {
            f1 = __builtin_fmaf(acc[nt][r], a1v[nt], f1);
            f2 = __builtin_fmaf(acc[nt][r], a2v[nt], f2);
        }
#pragma unroll
        for (int o = 1; o < 16; o <<= 1) {
            f1 += __shfl_xor(f1, o);
            f2 += __shfl_xor(f2, o);
        }
        float g2 = __builtin_amdgcn_exp2f(0.2f * LOG2E * f2);
        G2f[r] = g2;
        if (c == 0) {
            int i = i0 + g * 4 + r;
            Rc [head * N_NODES + i] = __builtin_amdgcn_exp2f(-0.8f * LOG2E * f1);
            Tc [head * N_NODES + i] = __builtin_amdgcn_exp2f( 0.8f * LOG2E * f2);
            G2b[head * N_NODES + i] = f2bf(g2);
        }
    }
    // --- Ht n-major store, G2-folded: Ht[(head*64+n)*4096 + i] = bf16(acc*G2_i)
#pragma unroll
    for (int nt = 0; nt < 4; ++nt) {
        union { ushort s[4]; bf16x4 v; } pk;
#pragma unroll
        for (int r = 0; r < 4; ++r) pk.s[r] = f2bf(acc[nt][r] * G2f[r]);
        *(bf16x4*)(Ht + ((size_t)head * 64 + nt * 16 + c) * N_NODES + i0 + g * 4) = pk.v;
    }
}

// ---------------- masked flash attention ------------------------------------
// Block = 4 waves x 32 i-rows = 128 rows; mfma 32x32x16, JT=128 (2 barriers
// per 128 j). Per score: ONE fmax + branchless 3-op sign-mask (no vcc).
// z accumulated by a third MFMA against the bf16 G2 row (kills the serial
// z-add chain). All per-tile data staged via global_load_lds (zero VMEM in
// the compute loop, per-wave counted vmcnt exact).
__global__ __launch_bounds__(256)
__attribute__((amdgpu_waves_per_eu(4, 8)))
void k_attn(const ushort* __restrict__ Ht,
        const float* __restrict__ Rc, const float* __restrict__ Tc,
        const ushort* __restrict__ G2b, const unsigned* __restrict__ maskw,
        float* __restrict__ accP, float* __restrict__ Zp, int JS) {
    int rb = blockIdx.x, js = blockIdx.y, head = blockIdx.z;
    int t = threadIdx.x, wave = t >> 6, lane = t & 63;
    int r32 = lane & 31, half = lane >> 5;
    int i0b = rb * 128;
    int i0w = i0b + wave * 32;
    int irow = i0w + r32;
    int jcount = N_NODES / JS;
    int j0 = js * jcount;
    int ntiles = jcount / JT;
    const float R = Rc[head * N_NODES + irow];

    __shared__ ushort Hs[2][64 * JT];           // 2 x 16 KB, swizzled chunks
    __shared__ unsigned Ms[2][512];             // 2 x 2 KB: [128 rows][4 words]
    __shared__ float Ts[2][JT];                 // 2 x 512 B
    __shared__ ushort G2s[2][JT];               // 2 x 256 B

    // H staging: wave w round s (0..3): rows n = (w*4+s)*4 + (lane>>4);
    // phys 16B-slot lane&15 holds logical chunk (lane&15)^(n&7)
    int nH = (wave * 4) * 4 + (lane >> 4);      // row for s=0; +4 per s
    const ushort* gspH[4];
#pragma unroll
    for (int s = 0; s < 4; ++s) {
        int n = nH + s * 4;
        gspH[s] = Ht + ((size_t)head * 64 + n) * N_NODES + j0
                + (((lane & 15) ^ (n & 7)) << 3);
    }
    // mask staging (wave 0, 8 rounds): row s*16+(lane>>2), word lane&3
    const unsigned* msrc[8];
#pragma unroll
    for (int s = 0; s < 8; ++s)
        msrc[s] = maskw + (size_t)(i0b + s * 16 + (lane >> 2)) * 128 + (j0 >> 5) + (lane & 3);
    const float*  tsrc = Tc  + (size_t)head * N_NODES + j0 + lane;       // wave 1
    const ushort* gsrc = G2b + (size_t)head * N_NODES + j0 + lane * 2;   // wave 2

    auto stage = [&](int b, int tile) {
        int go = tile * JT;
#pragma unroll
        for (int s = 0; s < 4; ++s)
            __builtin_amdgcn_global_load_lds((const unsigned*)(gspH[s] + go),
                    (unsigned*)&Hs[b][(wave * 4 + s) * 512], 16, 0, 0);
        if (wave == 0) {
#pragma unroll
            for (int s = 0; s < 8; ++s)
                __builtin_amdgcn_global_load_lds((const unsigned*)(msrc[s] + tile * 4),
                        (unsigned*)&Ms[b][s * 64], 4, 0, 0);
        } else if (wave == 1) {
#pragma unroll
            for (int s = 0; s < 2; ++s)
                __builtin_amdgcn_global_load_lds((const unsigned*)(tsrc + go + s * 64),
                        (unsigned*)&Ts[b][s * 64], 4, 0, 0);
        } else if (wave == 2) {
            __builtin_amdgcn_global_load_lds((const unsigned*)(gsrc + go),
                    (unsigned*)&G2s[b][0], 4, 0, 0);
        }
    };

    f32x16 acc0 = {}, acc1 = {}, acc2 = {};

    stage(0, 0);
    int buf = 0;
    for (int tile = 0; tile < ntiles; ++tile) {
        if (tile + 1 < ntiles) {
            stage(buf ^ 1, tile + 1);
            if (wave == 0)      asm volatile("s_waitcnt vmcnt(12)");
            else if (wave == 1) asm volatile("s_waitcnt vmcnt(6)");
            else if (wave == 2) asm volatile("s_waitcnt vmcnt(5)");
            else                asm volatile("s_waitcnt vmcnt(4)");
        } else {
            asm volatile("s_waitcnt vmcnt(0)");
        }
        __builtin_amdgcn_s_barrier();

        const char* hb = (const char*)&Hs[buf][0];
#pragma unroll
        for (int itr = 0; itr < JT / 16; ++itr) {
            unsigned phys = (unsigned)(((itr * 2 + half) ^ (r32 & 7)) << 4);
            bf16x8 b0 = *(const bf16x8*)(hb + r32 * 256 + phys);
            bf16x8 b1 = *(const bf16x8*)(hb + (32 + r32) * 256 + phys);
            bf16x8 bg = *(const bf16x8*)(&G2s[buf][itr * 16 + half * 8]);
            unsigned mword = Ms[buf][(wave * 32 + r32) * 4 + (itr >> 1)];
            unsigned mshift = mword >> ((itr & 1) * 16 + half * 8);
            const float* tp = &Ts[buf][itr * 16 + half * 8];
            float4 ta = *(const float4*)tp;
            float4 tb = *(const float4*)(tp + 4);
            float tv[8] = {ta.x, ta.y, ta.z, ta.w, tb.x, tb.y, tb.z, tb.w};
            float p[8];
#pragma unroll
            for (int e = 0; e < 8; ++e) {
                int sm = (int)(mshift << (31 - e)) >> 31;        // branchless mask
                float pe = fmaxf(tv[e], R);
                union { float f; int i; } pv; pv.f = pe;
                pv.i &= sm;
                p[e] = pv.f;
            }
            union { unsigned w[4]; bf16x8 v; } pa;
#pragma unroll
            for (int q = 0; q < 4; ++q)
                asm("v_cvt_pk_bf16_f32 %0, %1, %2"
                    : "=v"(pa.w[q]) : "v"(p[2 * q]), "v"(p[2 * q + 1]));
            acc0 = __builtin_amdgcn_mfma_f32_32x32x16_bf16(pa.v, b0, acc0, 0, 0, 0);
            acc1 = __builtin_amdgcn_mfma_f32_32x32x16_bf16(pa.v, b1, acc1, 0, 0, 0);
            acc2 = __builtin_amdgcn_mfma_f32_32x32x16_bf16(pa.v, bg, acc2, 0, 0, 0);
        }
        __builtin_amdgcn_s_barrier();
        buf ^= 1;
    }
    int slice = head * JS + js;
    // z from acc2 (every accumulator column holds the same row-sum)
    if (r32 == 0) {
#pragma unroll
        for (int reg = 0; reg < 16; ++reg) {
            int drow = (reg & 3) + 8 * (reg >> 2) + 4 * half;
            Zp[(size_t)slice * N_NODES + i0w + drow] = acc2[reg];
        }
    }
    float* ap = accP + ((size_t)slice * N_NODES + i0w) * 64;
#pragma unroll
    for (int reg = 0; reg < 16; ++reg) {
        int drow = (reg & 3) + 8 * (reg >> 2) + 4 * half;
        ap[drow * 64 + r32] = acc0[reg];
        ap[drow * 64 + 32 + r32] = acc1[reg];
    }
}

// ---------------- combine partials -------------------------------------------
__global__ __launch_bounds__(256) void k_combine1(const float* __restrict__ accP,
        const float* __restrict__ Zp, float* __restrict__ x2, int JS) {
    int idx = blockIdx.x * 256 + threadIdx.x;    // 8*4096*64
    int n = idx & 63, i = (idx >> 6) & 4095, h = idx >> 18;
    float s = 0.f, z = 0.f;
    for (int j = 0; j < JS; ++j) {
        int sl = h * JS + j;
        s += accP[((size_t)sl * N_NODES + i) * 64 + n];
        z += Zp[(size_t)sl * N_NODES + i];
    }
    float v = s / z;
    v = v > 0.f ? v : (__builtin_amdgcn_exp2f(v * LOG2E) - 1.f);   // elu
    x2[(size_t)i * 512 + h * 64 + n] = v;
}

__global__ __launch_bounds__(256) void k_combine2(const float* __restrict__ accP,
        const float* __restrict__ Zp, float* __restrict__ out, int JS) {
    int idx = blockIdx.x * 256 + threadIdx.x;    // 4096*64
    int n = idx & 63, i = idx >> 6;
    float s = 0.f, z = 0.f;
    for (int j = 0; j < JS; ++j) {
        s += accP[((size_t)j * N_NODES + i) * 64 + n];
        z += Zp[(size_t)j * N_NODES + i];
    }
    out[idx] = s / z;
}

extern "C" void kernel_launch(void* const* d_in, const int* in_sizes, int n_in,
                              void* d_out, int out_size, void* d_ws, size_t ws_size,
                              hipStream_t stream) {
    const float* features = (const float*)d_in[0];
    const float* adj      = (const float*)d_in[1];
    const float* W_heads  = (const float*)d_in[2];
    const float* a_heads  = (const float*)d_in[3];
    const float* W_out    = (const float*)d_in[4];
    const float* a_out    = (const float*)d_in[5];
    float* out = (float*)d_out;

    // fixed buffers ~16.4 MB; per-slice accP+Zp ~1.07 MB
    int JS1, JS2;
    if (ws_size >= 51800000)      { JS1 = 4; JS2 = 32; }   // slices 32
    else if (ws_size >= 34800000) { JS1 = 2; JS2 = 16; }
    else                          { JS1 = 1; JS2 = 8;  }
    int slices = (8 * JS1 > JS2) ? 8 * JS1 : JS2;

    char* ws = (char*)d_ws;
    size_t off = 0;
    auto alloc = [&](size_t bytes) -> void* {
        void* p = ws + off; off = (off + bytes + 255) & ~(size_t)255; return p;
    };
    unsigned* maskw = (unsigned*)alloc((size_t)N_NODES * 128 * 4);
    ushort* Ht1 = (ushort*)alloc((size_t)8 * 64 * N_NODES * 2);   // n-major
    ushort* Ht2 = (ushort*)alloc((size_t)64 * N_NODES * 2);
    float* Rc1  = (float*)alloc((size_t)8 * N_NODES * 4);
    float* Tc1  = (float*)alloc((size_t)8 * N_NODES * 4);
    ushort* G2b1 = (ushort*)alloc((size_t)8 * N_NODES * 2);
    float* Rc2  = (float*)alloc((size_t)N_NODES * 4);
    float* Tc2  = (float*)alloc((size_t)N_NODES * 4);
    ushort* G2b2 = (ushort*)alloc((size_t)N_NODES * 2);
    ushort* Wh1 = (ushort*)alloc((size_t)8 * 64 * 256 * 2);
    ushort* Wl1 = (ushort*)alloc((size_t)8 * 64 * 256 * 2);
    ushort* Wh2 = (ushort*)alloc((size_t)64 * 512 * 2);
    ushort* Wl2 = (ushort*)alloc((size_t)64 * 512 * 2);
    float* x2   = (float*)alloc((size_t)N_NODES * 512 * 4);
    float* accP = (float*)alloc((size_t)slices * N_NODES * 64 * 4);
    float* Zp   = (float*)alloc((size_t)slices * N_NODES * 4);

    hipLaunchKernelGGL(k_pack_mask, dim3(N_NODES * 128 / 256), dim3(256), 0, stream, adj, maskw);
    hipLaunchKernelGGL(k_prep_w, dim3((8 * 256 * 64 + 255) / 256), dim3(256), 0, stream,
                       W_heads, Wh1, Wl1, 8, 8 * 256 * 64);
    hipLaunchKernelGGL(k_prep_w, dim3((512 * 64 + 255) / 256), dim3(256), 0, stream,
                       W_out, Wh2, Wl2, 9, 512 * 64);
    // layer 1
    hipLaunchKernelGGL(k_gemm_h, dim3(64, 8), dim3(256), 0, stream,
                       features, Wh1, Wl1, a_heads, Ht1, Rc1, Tc1, G2b1, 256);
    hipLaunchKernelGGL(k_attn, dim3(32, JS1, 8), dim3(256), 0, stream,
                       Ht1, Rc1, Tc1, G2b1, maskw, accP, Zp, JS1);
    hipLaunchKernelGGL(k_combine1, dim3(8 * N_NODES * 64 / 256), dim3(256), 0, stream,
                       accP, Zp, x2, JS1);
    // layer 2
    hipLaunchKernelGGL(k_gemm_h, dim3(64, 1), dim3(256), 0, stream,
                       x2, Wh2, Wl2, a_out, Ht2, Rc2, Tc2, G2b2, 512);
    hipLaunchKernelGGL(k_attn, dim3(32, JS2, 1), dim3(256), 0, stream,
                       Ht2, Rc2, Tc2, G2b2, maskw, accP, Zp, JS2);
    hipLaunchKernelGGL(k_combine2, dim3(N_NODES * 64 / 256), dim3(256), 0, stream,
                       accP, Zp, out, JS2);
}

// Round 9
// 130.020 us; speedup vs baseline: 1.5831x; 1.0754x over previous
//
#include <hip/hip_runtime.h>
#include <hip/hip_bf16.h>

#define N_NODES 4096
#define LOG2E 1.44269504088896340736f
#define JT 128                      // j-tile staged in LDS per block (dbuf)

typedef __attribute__((ext_vector_type(8))) short bf16x8;
typedef __attribute__((ext_vector_type(4))) short bf16x4;
typedef __attribute__((ext_vector_type(4))) float f32x4;
typedef __attribute__((ext_vector_type(16))) float f32x16;

static __device__ __forceinline__ ushort f2bf(float x) {
    union { float f; unsigned u; } v; v.f = x;
    unsigned u = v.u;
    return (ushort)((u + 0x7FFFu + ((u >> 16) & 1u)) >> 16);   // RNE
}

// ---------------- mask pack: adj [4096][4096] f32 -> bits [4096][128] u32 ----
__global__ __launch_bounds__(256) void k_pack_mask(const float* __restrict__ adj,
                                                   unsigned* __restrict__ maskw) {
    int idx = blockIdx.x * 256 + threadIdx.x;          // 4096*128 words
    int row = idx >> 7, w = idx & 127;
    const float4* ap = (const float4*)(adj + (size_t)row * N_NODES + w * 32);
    unsigned bits = 0;
#pragma unroll
    for (int q = 0; q < 8; ++q) {
        float4 v = ap[q];
        bits |= (v.x > 0.f ? 1u : 0u) << (q * 4 + 0);
        bits |= (v.y > 0.f ? 1u : 0u) << (q * 4 + 1);
        bits |= (v.z > 0.f ? 1u : 0u) << (q * 4 + 2);
        bits |= (v.w > 0.f ? 1u : 0u) << (q * 4 + 3);
    }
    maskw[idx] = bits;
}

// ---------------- W [h][K][64] f32 -> Wt hi/lo bf16 [h][64][K] (K-major) -----
__global__ void k_prep_w(const float* __restrict__ W, ushort* __restrict__ Wh,
                         ushort* __restrict__ Wl, int kshift, int total) {
    int idx = blockIdx.x * 256 + threadIdx.x;
    if (idx >= total) return;
    int K = 1 << kshift;
    int n = idx & 63;
    int k = (idx >> 6) & (K - 1);
    int h = idx >> (6 + kshift);
    float v = W[idx];
    ushort hi = f2bf(v);
    union { unsigned u; float f; } hv; hv.u = ((unsigned)hi) << 16;
    ushort lo = f2bf(v - hv.f);
    size_t dst = ((size_t)h * 64 + n) * K + k;
    Wh[dst] = hi; Wl[dst] = lo;
}

// ---------------- H = X @ W (3-term split bf16 MFMA), 8-way K-split ----------
// Block = 512 threads = 8 waves; block owns a 16-row tile (grid.x = N/16);
// wave w computes a partial over K/8; LDS-reduce (padded, conflict-free);
// wave 0 does the epilogue: factorized-softmax per-node factors
//   T = exp(0.8 f2), R = exp(-0.8 f1), G2 = exp(0.2 f2)
// and the G2-folded n-major Ht store (w_ij = G2_j*max(T_j,R_i), exact). ------
__global__ __launch_bounds__(512) void k_gemm_h(const float* __restrict__ X,
        const ushort* __restrict__ Wh, const ushort* __restrict__ Wl,
        const float* __restrict__ a,
        ushort* __restrict__ Ht, float* __restrict__ Rc,
        float* __restrict__ Tc, ushort* __restrict__ G2b, int K) {
    int head = blockIdx.y;
    int t = threadIdx.x, wave = t >> 6, lane = t & 63;
    int c = lane & 15, g = lane >> 4;
    int i0 = blockIdx.x * 16;
    int kq = K >> 3;                            // per-wave K range
    int kbeg = wave * kq;
    const float* xrow = X + (size_t)(i0 + c) * K;
    f32x4 acc[4] = {};
    for (int k0 = kbeg; k0 < kbeg + kq; k0 += 32) {
        const float4* xp = (const float4*)(xrow + k0 + g * 8);
        float4 xa = xp[0], xb = xp[1];
        float xs[8] = {xa.x, xa.y, xa.z, xa.w, xb.x, xb.y, xb.z, xb.w};
        union { ushort s[8]; bf16x8 v; } ah, al;
#pragma unroll
        for (int e = 0; e < 8; ++e) {
            ushort hb = f2bf(xs[e]);
            ah.s[e] = hb;
            union { unsigned u; float f; } hv; hv.u = ((unsigned)hb) << 16;
            al.s[e] = f2bf(xs[e] - hv.f);
        }
#pragma unroll
        for (int nt = 0; nt < 4; ++nt) {
            size_t boff = ((size_t)head * 64 + nt * 16 + c) * K + k0 + g * 8;
            bf16x8 bh = *(const bf16x8*)(Wh + boff);
            bf16x8 bl = *(const bf16x8*)(Wl + boff);
            acc[nt] = __builtin_amdgcn_mfma_f32_16x16x32_bf16(ah.v, bh, acc[nt], 0, 0, 0);
            acc[nt] = __builtin_amdgcn_mfma_f32_16x16x32_bf16(al.v, bh, acc[nt], 0, 0, 0);
            acc[nt] = __builtin_amdgcn_mfma_f32_16x16x32_bf16(ah.v, bl, acc[nt], 0, 0, 0);
        }
    }
    // --- cross-wave K reduction (pad 16->17 to spread banks) ---
    __shared__ float red[8][64][17];            // ~34.8 KB
#pragma unroll
    for (int nt = 0; nt < 4; ++nt)
#pragma unroll
        for (int r = 0; r < 4; ++r)
            red[wave][lane][nt * 4 + r] = acc[nt][r];
    __syncthreads();
    if (wave != 0) return;
#pragma unroll
    for (int nt = 0; nt < 4; ++nt)
#pragma unroll
        for (int r = 0; r < 4; ++r) {
            float s = 0.f;
#pragma unroll
            for (int w = 0; w < 8; ++w) s += red[w][lane][nt * 4 + r];
            acc[nt][r] = s;
        }
    // --- fused f1/f2 row-dots -> per-node factors
    float a1v[4], a2v[4];
#pragma unroll
    for (int nt = 0; nt < 4; ++nt) {
        a1v[nt] = a[head * 128 + nt * 16 + c];
        a2v[nt] = a[head * 128 + 64 + nt * 16 + c];
    }
    float G2f[4];
#pragma unroll
    for (int r = 0; r < 4; ++r) {
        float f1 = 0.f, f2 = 0.f;
#pragma unroll
        for (int nt = 0; nt < 4; ++nt) {
            f1 = __builtin_fmaf(acc[nt][r], a1v[nt], f1);
            f2 = __builtin_fmaf(acc[nt][r], a2v[nt], f2);
        }
#pragma unroll
        for (int o = 1; o < 16; o <<= 1) {
            f1 += __shfl_xor(f1, o);
            f2 += __shfl_xor(f2, o);
        }
        float g2 = __builtin_amdgcn_exp2f(0.2f * LOG2E * f2);
        G2f[r] = g2;
        if (c == 0) {
            int i = i0 + g * 4 + r;
            Rc [head * N_NODES + i] = __builtin_amdgcn_exp2f(-0.8f * LOG2E * f1);
            Tc [head * N_NODES + i] = __builtin_amdgcn_exp2f( 0.8f * LOG2E * f2);
            G2b[head * N_NODES + i] = f2bf(g2);
        }
    }
    // --- Ht n-major store, G2-folded
#pragma unroll
    for (int nt = 0; nt < 4; ++nt) {
        union { ushort s[4]; bf16x4 v; } pk;
#pragma unroll
        for (int r = 0; r < 4; ++r) pk.s[r] = f2bf(acc[nt][r] * G2f[r]);
        *(bf16x4*)(Ht + ((size_t)head * 64 + nt * 16 + c) * N_NODES + i0 + g * 4) = pk.v;
    }
}

// ---------------- masked flash attention (unchanged from R8) -----------------
__global__ __launch_bounds__(256)
__attribute__((amdgpu_waves_per_eu(4, 8)))
void k_attn(const ushort* __restrict__ Ht,
        const float* __restrict__ Rc, const float* __restrict__ Tc,
        const ushort* __restrict__ G2b, const unsigned* __restrict__ maskw,
        float* __restrict__ accP, float* __restrict__ Zp, int JS) {
    int rb = blockIdx.x, js = blockIdx.y, head = blockIdx.z;
    int t = threadIdx.x, wave = t >> 6, lane = t & 63;
    int r32 = lane & 31, half = lane >> 5;
    int i0b = rb * 128;
    int i0w = i0b + wave * 32;
    int irow = i0w + r32;
    int jcount = N_NODES / JS;
    int j0 = js * jcount;
    int ntiles = jcount / JT;
    const float R = Rc[head * N_NODES + irow];

    __shared__ ushort Hs[2][64 * JT];           // 2 x 16 KB, swizzled chunks
    __shared__ unsigned Ms[2][512];             // 2 x 2 KB: [128 rows][4 words]
    __shared__ float Ts[2][JT];                 // 2 x 512 B
    __shared__ ushort G2s[2][JT];               // 2 x 256 B

    int nH = (wave * 4) * 4 + (lane >> 4);      // row for s=0; +4 per s
    const ushort* gspH[4];
#pragma unroll
    for (int s = 0; s < 4; ++s) {
        int n = nH + s * 4;
        gspH[s] = Ht + ((size_t)head * 64 + n) * N_NODES + j0
                + (((lane & 15) ^ (n & 7)) << 3);
    }
    const unsigned* msrc[8];
#pragma unroll
    for (int s = 0; s < 8; ++s)
        msrc[s] = maskw + (size_t)(i0b + s * 16 + (lane >> 2)) * 128 + (j0 >> 5) + (lane & 3);
    const float*  tsrc = Tc  + (size_t)head * N_NODES + j0 + lane;       // wave 1
    const ushort* gsrc = G2b + (size_t)head * N_NODES + j0 + lane * 2;   // wave 2

    auto stage = [&](int b, int tile) {
        int go = tile * JT;
#pragma unroll
        for (int s = 0; s < 4; ++s)
            __builtin_amdgcn_global_load_lds((const unsigned*)(gspH[s] + go),
                    (unsigned*)&Hs[b][(wave * 4 + s) * 512], 16, 0, 0);
        if (wave == 0) {
#pragma unroll
            for (int s = 0; s < 8; ++s)
                __builtin_amdgcn_global_load_lds((const unsigned*)(msrc[s] + tile * 4),
                        (unsigned*)&Ms[b][s * 64], 4, 0, 0);
        } else if (wave == 1) {
#pragma unroll
            for (int s = 0; s < 2; ++s)
                __builtin_amdgcn_global_load_lds((const unsigned*)(tsrc + go + s * 64),
                        (unsigned*)&Ts[b][s * 64], 4, 0, 0);
        } else if (wave == 2) {
            __builtin_amdgcn_global_load_lds((const unsigned*)(gsrc + go),
                    (unsigned*)&G2s[b][0], 4, 0, 0);
        }
    };

    f32x16 acc0 = {}, acc1 = {}, acc2 = {};

    stage(0, 0);
    int buf = 0;
    for (int tile = 0; tile < ntiles; ++tile) {
        if (tile + 1 < ntiles) {
            stage(buf ^ 1, tile + 1);
            if (wave == 0)      asm volatile("s_waitcnt vmcnt(12)");
            else if (wave == 1) asm volatile("s_waitcnt vmcnt(6)");
            else if (wave == 2) asm volatile("s_waitcnt vmcnt(5)");
            else                asm volatile("s_waitcnt vmcnt(4)");
        } else {
            asm volatile("s_waitcnt vmcnt(0)");
        }
        __builtin_amdgcn_s_barrier();

        const char* hb = (const char*)&Hs[buf][0];
#pragma unroll
        for (int itr = 0; itr < JT / 16; ++itr) {
            unsigned phys = (unsigned)(((itr * 2 + half) ^ (r32 & 7)) << 4);
            bf16x8 b0 = *(const bf16x8*)(hb + r32 * 256 + phys);
            bf16x8 b1 = *(const bf16x8*)(hb + (32 + r32) * 256 + phys);
            bf16x8 bg = *(const bf16x8*)(&G2s[buf][itr * 16 + half * 8]);
            unsigned mword = Ms[buf][(wave * 32 + r32) * 4 + (itr >> 1)];
            unsigned mshift = mword >> ((itr & 1) * 16 + half * 8);
            const float* tp = &Ts[buf][itr * 16 + half * 8];
            float4 ta = *(const float4*)tp;
            float4 tb = *(const float4*)(tp + 4);
            float tv[8] = {ta.x, ta.y, ta.z, ta.w, tb.x, tb.y, tb.z, tb.w};
            float p[8];
#pragma unroll
            for (int e = 0; e < 8; ++e) {
                int sm = (int)(mshift << (31 - e)) >> 31;        // branchless mask
                float pe = fmaxf(tv[e], R);
                union { float f; int i; } pv; pv.f = pe;
                pv.i &= sm;
                p[e] = pv.f;
            }
            union { unsigned w[4]; bf16x8 v; } pa;
#pragma unroll
            for (int q = 0; q < 4; ++q)
                asm("v_cvt_pk_bf16_f32 %0, %1, %2"
                    : "=v"(pa.w[q]) : "v"(p[2 * q]), "v"(p[2 * q + 1]));
            acc0 = __builtin_amdgcn_mfma_f32_32x32x16_bf16(pa.v, b0, acc0, 0, 0, 0);
            acc1 = __builtin_amdgcn_mfma_f32_32x32x16_bf16(pa.v, b1, acc1, 0, 0, 0);
            acc2 = __builtin_amdgcn_mfma_f32_32x32x16_bf16(pa.v, bg, acc2, 0, 0, 0);
        }
        __builtin_amdgcn_s_barrier();
        buf ^= 1;
    }
    int slice = head * JS + js;
    if (r32 == 0) {
#pragma unroll
        for (int reg = 0; reg < 16; ++reg) {
            int drow = (reg & 3) + 8 * (reg >> 2) + 4 * half;
            Zp[(size_t)slice * N_NODES + i0w + drow] = acc2[reg];
        }
    }
    float* ap = accP + ((size_t)slice * N_NODES + i0w) * 64;
#pragma unroll
    for (int reg = 0; reg < 16; ++reg) {
        int drow = (reg & 3) + 8 * (reg >> 2) + 4 * half;
        ap[drow * 64 + r32] = acc0[reg];
        ap[drow * 64 + 32 + r32] = acc1[reg];
    }
}

// ---------------- combine partials -------------------------------------------
__global__ __launch_bounds__(256) void k_combine1(const float* __restrict__ accP,
        const float* __restrict__ Zp, float* __restrict__ x2, int JS) {
    int idx = blockIdx.x * 256 + threadIdx.x;    // 8*4096*64
    int n = idx & 63, i = (idx >> 6) & 4095, h = idx >> 18;
    float s = 0.f, z = 0.f;
    for (int j = 0; j < JS; ++j) {
        int sl = h * JS + j;
        s += accP[((size_t)sl * N_NODES + i) * 64 + n];
        z += Zp[(size_t)sl * N_NODES + i];
    }
    float v = s / z;
    v = v > 0.f ? v : (__builtin_amdgcn_exp2f(v * LOG2E) - 1.f);   // elu
    x2[(size_t)i * 512 + h * 64 + n] = v;
}

__global__ __launch_bounds__(256) void k_combine2(const float* __restrict__ accP,
        const float* __restrict__ Zp, float* __restrict__ out, int JS) {
    int idx = blockIdx.x * 256 + threadIdx.x;    // 4096*64
    int n = idx & 63, i = idx >> 6;
    float s = 0.f, z = 0.f;
    for (int j = 0; j < JS; ++j) {
        s += accP[((size_t)j * N_NODES + i) * 64 + n];
        z += Zp[(size_t)j * N_NODES + i];
    }
    out[idx] = s / z;
}

extern "C" void kernel_launch(void* const* d_in, const int* in_sizes, int n_in,
                              void* d_out, int out_size, void* d_ws, size_t ws_size,
                              hipStream_t stream) {
    const float* features = (const float*)d_in[0];
    const float* adj      = (const float*)d_in[1];
    const float* W_heads  = (const float*)d_in[2];
    const float* a_heads  = (const float*)d_in[3];
    const float* W_out    = (const float*)d_in[4];
    const float* a_out    = (const float*)d_in[5];
    float* out = (float*)d_out;

    // fixed buffers ~16.4 MB; per-slice accP+Zp ~1.07 MB
    int JS1, JS2;
    if (ws_size >= 51800000)      { JS1 = 4; JS2 = 32; }   // slices 32
    else if (ws_size >= 34800000) { JS1 = 2; JS2 = 16; }
    else                          { JS1 = 1; JS2 = 8;  }
    int slices = (8 * JS1 > JS2) ? 8 * JS1 : JS2;

    char* ws = (char*)d_ws;
    size_t off = 0;
    auto alloc = [&](size_t bytes) -> void* {
        void* p = ws + off; off = (off + bytes + 255) & ~(size_t)255; return p;
    };
    unsigned* maskw = (unsigned*)alloc((size_t)N_NODES * 128 * 4);
    ushort* Ht1 = (ushort*)alloc((size_t)8 * 64 * N_NODES * 2);   // n-major
    ushort* Ht2 = (ushort*)alloc((size_t)64 * N_NODES * 2);
    float* Rc1  = (float*)alloc((size_t)8 * N_NODES * 4);
    float* Tc1  = (float*)alloc((size_t)8 * N_NODES * 4);
    ushort* G2b1 = (ushort*)alloc((size_t)8 * N_NODES * 2);
    float* Rc2  = (float*)alloc((size_t)N_NODES * 4);
    float* Tc2  = (float*)alloc((size_t)N_NODES * 4);
    ushort* G2b2 = (ushort*)alloc((size_t)N_NODES * 2);
    ushort* Wh1 = (ushort*)alloc((size_t)8 * 64 * 256 * 2);
    ushort* Wl1 = (ushort*)alloc((size_t)8 * 64 * 256 * 2);
    ushort* Wh2 = (ushort*)alloc((size_t)64 * 512 * 2);
    ushort* Wl2 = (ushort*)alloc((size_t)64 * 512 * 2);
    float* x2   = (float*)alloc((size_t)N_NODES * 512 * 4);
    float* accP = (float*)alloc((size_t)slices * N_NODES * 64 * 4);
    float* Zp   = (float*)alloc((size_t)slices * N_NODES * 4);

    hipLaunchKernelGGL(k_pack_mask, dim3(N_NODES * 128 / 256), dim3(256), 0, stream, adj, maskw);
    hipLaunchKernelGGL(k_prep_w, dim3((8 * 256 * 64 + 255) / 256), dim3(256), 0, stream,
                       W_heads, Wh1, Wl1, 8, 8 * 256 * 64);
    hipLaunchKernelGGL(k_prep_w, dim3((512 * 64 + 255) / 256), dim3(256), 0, stream,
                       W_out, Wh2, Wl2, 9, 512 * 64);
    // layer 1
    hipLaunchKernelGGL(k_gemm_h, dim3(N_NODES / 16, 8), dim3(512), 0, stream,
                       features, Wh1, Wl1, a_heads, Ht1, Rc1, Tc1, G2b1, 256);
    hipLaunchKernelGGL(k_attn, dim3(32, JS1, 8), dim3(256), 0, stream,
                       Ht1, Rc1, Tc1, G2b1, maskw, accP, Zp, JS1);
    hipLaunchKernelGGL(k_combine1, dim3(8 * N_NODES * 64 / 256), dim3(256), 0, stream,
                       accP, Zp, x2, JS1);
    // layer 2
    hipLaunchKernelGGL(k_gemm_h, dim3(N_NODES / 16, 1), dim3(512), 0, stream,
                       x2, Wh2, Wl2, a_out, Ht2, Rc2, Tc2, G2b2, 512);
    hipLaunchKernelGGL(k_attn, dim3(32, JS2, 1), dim3(256), 0, stream,
                       Ht2, Rc2, Tc2, G2b2, maskw, accP, Zp, JS2);
    hipLaunchKernelGGL(k_combine2, dim3(N_NODES * 64 / 256), dim3(256), 0, stream,
                       accP, Zp, out, JS2);
}

// Round 10
// 121.561 us; speedup vs baseline: 1.6932x; 1.0696x over previous
//
#include <hip/hip_runtime.h>
#include <hip/hip_bf16.h>

#define N_NODES 4096
#define LOG2E 1.44269504088896340736f
#define JT 128                      // j-tile staged in LDS per block (dbuf)

typedef __attribute__((ext_vector_type(8))) short bf16x8;
typedef __attribute__((ext_vector_type(4))) short bf16x4;
typedef __attribute__((ext_vector_type(4))) float f32x4;
typedef __attribute__((ext_vector_type(16))) float f32x16;

static __device__ __forceinline__ ushort f2bf(float x) {
    union { float f; unsigned u; } v; v.f = x;
    unsigned u = v.u;
    return (ushort)((u + 0x7FFFu + ((u >> 16) & 1u)) >> 16);   // RNE
}

// ---------------- fused prologue: pack_mask + prep_w(heads) + prep_w(out) ----
// blocks [0,2048): adj -> mask bits; [2048,2560): W_heads -> Wh1/Wl1 (K=256);
// [2560,2688): W_out -> Wh2/Wl2 (K=512). One dispatch instead of three.
__global__ __launch_bounds__(256) void k_prologue(const float* __restrict__ adj,
        unsigned* __restrict__ maskw,
        const float* __restrict__ W1, ushort* __restrict__ Wh1, ushort* __restrict__ Wl1,
        const float* __restrict__ W2, ushort* __restrict__ Wh2, ushort* __restrict__ Wl2) {
    int b = blockIdx.x, t = threadIdx.x;
    if (b < 2048) {
        int idx = b * 256 + t;                       // 4096*128 words
        int row = idx >> 7, w = idx & 127;
        const float4* ap = (const float4*)(adj + (size_t)row * N_NODES + w * 32);
        unsigned bits = 0;
#pragma unroll
        for (int q = 0; q < 8; ++q) {
            float4 v = ap[q];
            bits |= (v.x > 0.f ? 1u : 0u) << (q * 4 + 0);
            bits |= (v.y > 0.f ? 1u : 0u) << (q * 4 + 1);
            bits |= (v.z > 0.f ? 1u : 0u) << (q * 4 + 2);
            bits |= (v.w > 0.f ? 1u : 0u) << (q * 4 + 3);
        }
        maskw[idx] = bits;
    } else {
        const float* W; ushort *Wh, *Wl; int idx, kshift;
        if (b < 2560) { W = W1; Wh = Wh1; Wl = Wl1; idx = (b - 2048) * 256 + t; kshift = 8; }
        else          { W = W2; Wh = Wh2; Wl = Wl2; idx = (b - 2560) * 256 + t; kshift = 9; }
        int K = 1 << kshift;
        int n = idx & 63;
        int k = (idx >> 6) & (K - 1);
        int h = idx >> (6 + kshift);
        float v = W[idx];
        ushort hi = f2bf(v);
        union { unsigned u; float f; } hv; hv.u = ((unsigned)hi) << 16;
        ushort lo = f2bf(v - hv.f);
        size_t dst = ((size_t)h * 64 + n) * K + k;
        Wh[dst] = hi; Wl[dst] = lo;
    }
}

// ---------------- layer-1 H = X @ W (3-term split bf16 MFMA), 8-way K-split --
// Block = 512 thr = 8 waves; block owns 16 rows; wave w partials K/8; LDS
// reduce; wave 0 epilogue: factors T=exp(.8 f2), R=exp(-.8 f1), G2=exp(.2 f2)
// and G2-folded n-major Ht (w_ij = G2_j*max(T_j,R_i), exact identity). -------
__global__ __launch_bounds__(512) void k_gemm_h(const float* __restrict__ X,
        const ushort* __restrict__ Wh, const ushort* __restrict__ Wl,
        const float* __restrict__ a,
        ushort* __restrict__ Ht, float* __restrict__ Rc,
        float* __restrict__ Tc, ushort* __restrict__ G2b, int K) {
    int head = blockIdx.y;
    int t = threadIdx.x, wave = t >> 6, lane = t & 63;
    int c = lane & 15, g = lane >> 4;
    int i0 = blockIdx.x * 16;
    int kq = K >> 3;
    int kbeg = wave * kq;
    const float* xrow = X + (size_t)(i0 + c) * K;
    f32x4 acc[4] = {};
    for (int k0 = kbeg; k0 < kbeg + kq; k0 += 32) {
        const float4* xp = (const float4*)(xrow + k0 + g * 8);
        float4 xa = xp[0], xb = xp[1];
        float xs[8] = {xa.x, xa.y, xa.z, xa.w, xb.x, xb.y, xb.z, xb.w};
        union { ushort s[8]; bf16x8 v; } ah, al;
#pragma unroll
        for (int e = 0; e < 8; ++e) {
            ushort hb = f2bf(xs[e]);
            ah.s[e] = hb;
            union { unsigned u; float f; } hv; hv.u = ((unsigned)hb) << 16;
            al.s[e] = f2bf(xs[e] - hv.f);
        }
#pragma unroll
        for (int nt = 0; nt < 4; ++nt) {
            size_t boff = ((size_t)head * 64 + nt * 16 + c) * K + k0 + g * 8;
            bf16x8 bh = *(const bf16x8*)(Wh + boff);
            bf16x8 bl = *(const bf16x8*)(Wl + boff);
            acc[nt] = __builtin_amdgcn_mfma_f32_16x16x32_bf16(ah.v, bh, acc[nt], 0, 0, 0);
            acc[nt] = __builtin_amdgcn_mfma_f32_16x16x32_bf16(al.v, bh, acc[nt], 0, 0, 0);
            acc[nt] = __builtin_amdgcn_mfma_f32_16x16x32_bf16(ah.v, bl, acc[nt], 0, 0, 0);
        }
    }
    __shared__ float red[8][64][17];
#pragma unroll
    for (int nt = 0; nt < 4; ++nt)
#pragma unroll
        for (int r = 0; r < 4; ++r)
            red[wave][lane][nt * 4 + r] = acc[nt][r];
    __syncthreads();
    if (wave != 0) return;
#pragma unroll
    for (int nt = 0; nt < 4; ++nt)
#pragma unroll
        for (int r = 0; r < 4; ++r) {
            float s = 0.f;
#pragma unroll
            for (int w = 0; w < 8; ++w) s += red[w][lane][nt * 4 + r];
            acc[nt][r] = s;
        }
    float a1v[4], a2v[4];
#pragma unroll
    for (int nt = 0; nt < 4; ++nt) {
        a1v[nt] = a[head * 128 + nt * 16 + c];
        a2v[nt] = a[head * 128 + 64 + nt * 16 + c];
    }
    float G2f[4];
#pragma unroll
    for (int r = 0; r < 4; ++r) {
        float f1 = 0.f, f2 = 0.f;
#pragma unroll
        for (int nt = 0; nt < 4; ++nt) {
            f1 = __builtin_fmaf(acc[nt][r], a1v[nt], f1);
            f2 = __builtin_fmaf(acc[nt][r], a2v[nt], f2);
        }
#pragma unroll
        for (int o = 1; o < 16; o <<= 1) {
            f1 += __shfl_xor(f1, o);
            f2 += __shfl_xor(f2, o);
        }
        float g2 = __builtin_amdgcn_exp2f(0.2f * LOG2E * f2);
        G2f[r] = g2;
        if (c == 0) {
            int i = i0 + g * 4 + r;
            Rc [head * N_NODES + i] = __builtin_amdgcn_exp2f(-0.8f * LOG2E * f1);
            Tc [head * N_NODES + i] = __builtin_amdgcn_exp2f( 0.8f * LOG2E * f2);
            G2b[head * N_NODES + i] = f2bf(g2);
        }
    }
#pragma unroll
    for (int nt = 0; nt < 4; ++nt) {
        union { ushort s[4]; bf16x4 v; } pk;
#pragma unroll
        for (int r = 0; r < 4; ++r) pk.s[r] = f2bf(acc[nt][r] * G2f[r]);
        *(bf16x4*)(Ht + ((size_t)head * 64 + nt * 16 + c) * N_NODES + i0 + g * 4) = pk.v;
    }
}

// ---------------- layer-2 GEMM with fused combine1 ---------------------------
// x2[i][k] = elu(accP-sum / z) computed inline (wave w's K-slice == head w, so
// z is one scalar per row per wave). Deletes combine1 dispatch + x2 traffic.
__global__ __launch_bounds__(512) void k_gemm2(const float* __restrict__ accP,
        const float* __restrict__ Zp, int JS1,
        const ushort* __restrict__ Wh, const ushort* __restrict__ Wl,
        const float* __restrict__ a,
        ushort* __restrict__ Ht, float* __restrict__ Rc,
        float* __restrict__ Tc, ushort* __restrict__ G2b) {
    const int K = 512;
    int t = threadIdx.x, wave = t >> 6, lane = t & 63;
    int c = lane & 15, g = lane >> 4;
    int i0 = blockIdx.x * 16;
    int row = i0 + c;
    int hx = wave;                               // this wave's input head
    float z = 0.f;
    for (int js = 0; js < JS1; ++js)
        z += Zp[(size_t)(hx * JS1 + js) * N_NODES + row];
    float rz = 1.0f / z;
    f32x4 acc[4] = {};
#pragma unroll
    for (int ki = 0; ki < 2; ++ki) {
        int k0 = wave * 64 + ki * 32;
        int n0 = ki * 32 + g * 8;                // col within head block, 0..63
        float s[8] = {};
        for (int js = 0; js < JS1; ++js) {
            const float* apn = accP + ((size_t)(hx * JS1 + js) * N_NODES + row) * 64 + n0;
            float4 u0 = ((const float4*)apn)[0];
            float4 u1 = ((const float4*)apn)[1];
            s[0] += u0.x; s[1] += u0.y; s[2] += u0.z; s[3] += u0.w;
            s[4] += u1.x; s[5] += u1.y; s[6] += u1.z; s[7] += u1.w;
        }
        union { ushort sh[8]; bf16x8 v; } ah, al;
#pragma unroll
        for (int e = 0; e < 8; ++e) {
            float v = s[e] * rz;
            v = v > 0.f ? v : (__builtin_amdgcn_exp2f(v * LOG2E) - 1.f);   // elu
            ushort hb = f2bf(v);
            ah.sh[e] = hb;
            union { unsigned u; float f; } hv; hv.u = ((unsigned)hb) << 16;
            al.sh[e] = f2bf(v - hv.f);
        }
#pragma unroll
        for (int nt = 0; nt < 4; ++nt) {
            size_t boff = ((size_t)(nt * 16 + c)) * K + k0 + g * 8;
            bf16x8 bh = *(const bf16x8*)(Wh + boff);
            bf16x8 bl = *(const bf16x8*)(Wl + boff);
            acc[nt] = __builtin_amdgcn_mfma_f32_16x16x32_bf16(ah.v, bh, acc[nt], 0, 0, 0);
            acc[nt] = __builtin_amdgcn_mfma_f32_16x16x32_bf16(al.v, bh, acc[nt], 0, 0, 0);
            acc[nt] = __builtin_amdgcn_mfma_f32_16x16x32_bf16(ah.v, bl, acc[nt], 0, 0, 0);
        }
    }
    __shared__ float red[8][64][17];
#pragma unroll
    for (int nt = 0; nt < 4; ++nt)
#pragma unroll
        for (int r = 0; r < 4; ++r)
            red[wave][lane][nt * 4 + r] = acc[nt][r];
    __syncthreads();
    if (wave != 0) return;
#pragma unroll
    for (int nt = 0; nt < 4; ++nt)
#pragma unroll
        for (int r = 0; r < 4; ++r) {
            float s = 0.f;
#pragma unroll
            for (int w = 0; w < 8; ++w) s += red[w][lane][nt * 4 + r];
            acc[nt][r] = s;
        }
    float a1v[4], a2v[4];
#pragma unroll
    for (int nt = 0; nt < 4; ++nt) {
        a1v[nt] = a[nt * 16 + c];
        a2v[nt] = a[64 + nt * 16 + c];
    }
    float G2f[4];
#pragma unroll
    for (int r = 0; r < 4; ++r) {
        float f1 = 0.f, f2 = 0.f;
#pragma unroll
        for (int nt = 0; nt < 4; ++nt) {
            f1 = __builtin_fmaf(acc[nt][r], a1v[nt], f1);
            f2 = __builtin_fmaf(acc[nt][r], a2v[nt], f2);
        }
#pragma unroll
        for (int o = 1; o < 16; o <<= 1) {
            f1 += __shfl_xor(f1, o);
            f2 += __shfl_xor(f2, o);
        }
        float g2 = __builtin_amdgcn_exp2f(0.2f * LOG2E * f2);
        G2f[r] = g2;
        if (c == 0) {
            int i = i0 + g * 4 + r;
            Rc [i] = __builtin_amdgcn_exp2f(-0.8f * LOG2E * f1);
            Tc [i] = __builtin_amdgcn_exp2f( 0.8f * LOG2E * f2);
            G2b[i] = f2bf(g2);
        }
    }
#pragma unroll
    for (int nt = 0; nt < 4; ++nt) {
        union { ushort s[4]; bf16x4 v; } pk;
#pragma unroll
        for (int r = 0; r < 4; ++r) pk.s[r] = f2bf(acc[nt][r] * G2f[r]);
        *(bf16x4*)(Ht + ((size_t)(nt * 16 + c)) * N_NODES + i0 + g * 4) = pk.v;
    }
}

// ---------------- masked flash attention ------------------------------------
// 4 waves x 32 i-rows; mfma 32x32x16; factorized scores (1 fmax + 2-op mask);
// z via third MFMA. All tile data via global_load_lds, counted per-wave vmcnt.
// waves_per_eu(4,4): exactly-4 occupancy (grid = 4 blk/CU, LDS 38.4 KB) ->
// 128-VGPR budget for cross-itr ds_read pipelining (R9: (4,8) capped at 64).
// Mask: one ds_read_b128 per tile (statically indexed), not 8x conflicted b32.
__global__ __launch_bounds__(256)
__attribute__((amdgpu_waves_per_eu(4, 4)))
void k_attn(const ushort* __restrict__ Ht,
        const float* __restrict__ Rc, const float* __restrict__ Tc,
        const ushort* __restrict__ G2b, const unsigned* __restrict__ maskw,
        float* __restrict__ accP, float* __restrict__ Zp, int JS) {
    int rb = blockIdx.x, js = blockIdx.y, head = blockIdx.z;
    int t = threadIdx.x, wave = t >> 6, lane = t & 63;
    int r32 = lane & 31, half = lane >> 5;
    int i0b = rb * 128;
    int i0w = i0b + wave * 32;
    int irow = i0w + r32;
    int jcount = N_NODES / JS;
    int j0 = js * jcount;
    int ntiles = jcount / JT;
    const float R = Rc[head * N_NODES + irow];

    __shared__ ushort Hs[2][64 * JT];           // 2 x 16 KB, swizzled chunks
    __shared__ unsigned Ms[2][512];             // 2 x 2 KB: [128 rows][4 words]
    __shared__ float Ts[2][JT];                 // 2 x 512 B
    __shared__ ushort G2s[2][JT];               // 2 x 256 B

    int nH = (wave * 4) * 4 + (lane >> 4);      // row for s=0; +4 per s
    const ushort* gspH[4];
#pragma unroll
    for (int s = 0; s < 4; ++s) {
        int n = nH + s * 4;
        gspH[s] = Ht + ((size_t)head * 64 + n) * N_NODES + j0
                + (((lane & 15) ^ (n & 7)) << 3);
    }
    const unsigned* msrc[8];
#pragma unroll
    for (int s = 0; s < 8; ++s)
        msrc[s] = maskw + (size_t)(i0b + s * 16 + (lane >> 2)) * 128 + (j0 >> 5) + (lane & 3);
    const float*  tsrc = Tc  + (size_t)head * N_NODES + j0 + lane;       // wave 1
    const ushort* gsrc = G2b + (size_t)head * N_NODES + j0 + lane * 2;   // wave 2

    auto stage = [&](int b, int tile) {
        int go = tile * JT;
#pragma unroll
        for (int s = 0; s < 4; ++s)
            __builtin_amdgcn_global_load_lds((const unsigned*)(gspH[s] + go),
                    (unsigned*)&Hs[b][(wave * 4 + s) * 512], 16, 0, 0);
        if (wave == 0) {
#pragma unroll
            for (int s = 0; s < 8; ++s)
                __builtin_amdgcn_global_load_lds((const unsigned*)(msrc[s] + tile * 4),
                        (unsigned*)&Ms[b][s * 64], 4, 0, 0);
        } else if (wave == 1) {
#pragma unroll
            for (int s = 0; s < 2; ++s)
                __builtin_amdgcn_global_load_lds((const unsigned*)(tsrc + go + s * 64),
                        (unsigned*)&Ts[b][s * 64], 4, 0, 0);
        } else if (wave == 2) {
            __builtin_amdgcn_global_load_lds((const unsigned*)(gsrc + go),
                    (unsigned*)&G2s[b][0], 4, 0, 0);
        }
    };

    f32x16 acc0 = {}, acc1 = {}, acc2 = {};

    stage(0, 0);
    int buf = 0;
    for (int tile = 0; tile < ntiles; ++tile) {
        if (tile + 1 < ntiles) {
            stage(buf ^ 1, tile + 1);
            if (wave == 0)      asm volatile("s_waitcnt vmcnt(12)");
            else if (wave == 1) asm volatile("s_waitcnt vmcnt(6)");
            else if (wave == 2) asm volatile("s_waitcnt vmcnt(5)");
            else                asm volatile("s_waitcnt vmcnt(4)");
        } else {
            asm volatile("s_waitcnt vmcnt(0)");
        }
        __builtin_amdgcn_s_barrier();

        const char* hb = (const char*)&Hs[buf][0];
        // one b128 mask read per tile, statically indexed afterwards
        union { uint4 v; unsigned w[4]; } mw;
        mw.v = *(const uint4*)&Ms[buf][(wave * 32 + r32) * 4];
#pragma unroll
        for (int itr = 0; itr < JT / 16; ++itr) {
            unsigned phys = (unsigned)(((itr * 2 + half) ^ (r32 & 7)) << 4);
            bf16x8 b0 = *(const bf16x8*)(hb + r32 * 256 + phys);
            bf16x8 b1 = *(const bf16x8*)(hb + (32 + r32) * 256 + phys);
            bf16x8 bg = *(const bf16x8*)(&G2s[buf][itr * 16 + half * 8]);
            unsigned mword = mw.w[itr >> 1];
            unsigned mshift = mword >> ((itr & 1) * 16 + half * 8);
            const float* tp = &Ts[buf][itr * 16 + half * 8];
            float4 ta = *(const float4*)tp;
            float4 tb = *(const float4*)(tp + 4);
            float tv[8] = {ta.x, ta.y, ta.z, ta.w, tb.x, tb.y, tb.z, tb.w};
            float p[8];
#pragma unroll
            for (int e = 0; e < 8; ++e) {
                int sm = (int)(mshift << (31 - e)) >> 31;        // branchless mask
                float pe = fmaxf(tv[e], R);
                union { float f; int i; } pv; pv.f = pe;
                pv.i &= sm;
                p[e] = pv.f;
            }
            union { unsigned w[4]; bf16x8 v; } pa;
#pragma unroll
            for (int q = 0; q < 4; ++q)
                asm("v_cvt_pk_bf16_f32 %0, %1, %2"
                    : "=v"(pa.w[q]) : "v"(p[2 * q]), "v"(p[2 * q + 1]));
            acc0 = __builtin_amdgcn_mfma_f32_32x32x16_bf16(pa.v, b0, acc0, 0, 0, 0);
            acc1 = __builtin_amdgcn_mfma_f32_32x32x16_bf16(pa.v, b1, acc1, 0, 0, 0);
            acc2 = __builtin_amdgcn_mfma_f32_32x32x16_bf16(pa.v, bg, acc2, 0, 0, 0);
        }
        __builtin_amdgcn_s_barrier();
        buf ^= 1;
    }
    int slice = head * JS + js;
    if (r32 == 0) {
#pragma unroll
        for (int reg = 0; reg < 16; ++reg) {
            int drow = (reg & 3) + 8 * (reg >> 2) + 4 * half;
            Zp[(size_t)slice * N_NODES + i0w + drow] = acc2[reg];
        }
    }
    float* ap = accP + ((size_t)slice * N_NODES + i0w) * 64;
#pragma unroll
    for (int reg = 0; reg < 16; ++reg) {
        int drow = (reg & 3) + 8 * (reg >> 2) + 4 * half;
        ap[drow * 64 + r32] = acc0[reg];
        ap[drow * 64 + 32 + r32] = acc1[reg];
    }
}

// ---------------- combine partials (layer 2 / final output) ------------------
__global__ __launch_bounds__(256) void k_combine2(const float* __restrict__ accP,
        const float* __restrict__ Zp, float* __restrict__ out, int JS) {
    int idx = blockIdx.x * 256 + threadIdx.x;    // 4096*64
    int n = idx & 63, i = idx >> 6;
    float s = 0.f, z = 0.f;
    for (int j = 0; j < JS; ++j) {
        s += accP[((size_t)j * N_NODES + i) * 64 + n];
        z += Zp[(size_t)j * N_NODES + i];
    }
    out[idx] = s / z;
}

extern "C" void kernel_launch(void* const* d_in, const int* in_sizes, int n_in,
                              void* d_out, int out_size, void* d_ws, size_t ws_size,
                              hipStream_t stream) {
    const float* features = (const float*)d_in[0];
    const float* adj      = (const float*)d_in[1];
    const float* W_heads  = (const float*)d_in[2];
    const float* a_heads  = (const float*)d_in[3];
    const float* W_out    = (const float*)d_in[4];
    const float* a_out    = (const float*)d_in[5];
    float* out = (float*)d_out;

    // fixed buffers ~7.7 MB; per-slice accP+Zp ~1.05 MB
    int JS1, JS2;
    if (ws_size >= 43000000)      { JS1 = 4; JS2 = 32; }
    else if (ws_size >= 26000000) { JS1 = 2; JS2 = 16; }
    else                          { JS1 = 1; JS2 = 8;  }
    int slices = (8 * JS1 > JS2) ? 8 * JS1 : JS2;

    char* ws = (char*)d_ws;
    size_t off = 0;
    auto alloc = [&](size_t bytes) -> void* {
        void* p = ws + off; off = (off + bytes + 255) & ~(size_t)255; return p;
    };
    unsigned* maskw = (unsigned*)alloc((size_t)N_NODES * 128 * 4);
    ushort* Ht1 = (ushort*)alloc((size_t)8 * 64 * N_NODES * 2);   // n-major
    ushort* Ht2 = (ushort*)alloc((size_t)64 * N_NODES * 2);
    float* Rc1  = (float*)alloc((size_t)8 * N_NODES * 4);
    float* Tc1  = (float*)alloc((size_t)8 * N_NODES * 4);
    ushort* G2b1 = (ushort*)alloc((size_t)8 * N_NODES * 2);
    float* Rc2  = (float*)alloc((size_t)N_NODES * 4);
    float* Tc2  = (float*)alloc((size_t)N_NODES * 4);
    ushort* G2b2 = (ushort*)alloc((size_t)N_NODES * 2);
    ushort* Wh1 = (ushort*)alloc((size_t)8 * 64 * 256 * 2);
    ushort* Wl1 = (ushort*)alloc((size_t)8 * 64 * 256 * 2);
    ushort* Wh2 = (ushort*)alloc((size_t)64 * 512 * 2);
    ushort* Wl2 = (ushort*)alloc((size_t)64 * 512 * 2);
    float* accP = (float*)alloc((size_t)slices * N_NODES * 64 * 4);
    float* Zp   = (float*)alloc((size_t)slices * N_NODES * 4);

    hipLaunchKernelGGL(k_prologue, dim3(2688), dim3(256), 0, stream,
                       adj, maskw, W_heads, Wh1, Wl1, W_out, Wh2, Wl2);
    // layer 1
    hipLaunchKernelGGL(k_gemm_h, dim3(N_NODES / 16, 8), dim3(512), 0, stream,
                       features, Wh1, Wl1, a_heads, Ht1, Rc1, Tc1, G2b1, 256);
    hipLaunchKernelGGL(k_attn, dim3(32, JS1, 8), dim3(256), 0, stream,
                       Ht1, Rc1, Tc1, G2b1, maskw, accP, Zp, JS1);
    // layer 2 (combine1 fused into the GEMM)
    hipLaunchKernelGGL(k_gemm2, dim3(N_NODES / 16), dim3(512), 0, stream,
                       accP, Zp, JS1, Wh2, Wl2, a_out, Ht2, Rc2, Tc2, G2b2);
    hipLaunchKernelGGL(k_attn, dim3(32, JS2, 1), dim3(256), 0, stream,
                       Ht2, Rc2, Tc2, G2b2, maskw, accP, Zp, JS2);
    hipLaunchKernelGGL(k_combine2, dim3(N_NODES * 64 / 256), dim3(256), 0, stream,
                       accP, Zp, out, JS2);
}

// Round 11
// 121.255 us; speedup vs baseline: 1.6975x; 1.0025x over previous
//
#include <hip/hip_runtime.h>
#include <hip/hip_bf16.h>

#define N_NODES 4096
#define LOG2E 1.44269504088896340736f
#define JT 128                      // j-tile staged in LDS per block (dbuf)

typedef __attribute__((ext_vector_type(8))) short bf16x8;
typedef __attribute__((ext_vector_type(4))) short bf16x4;
typedef __attribute__((ext_vector_type(4))) float f32x4;
typedef __attribute__((ext_vector_type(16))) float f32x16;

static __device__ __forceinline__ ushort f2bf(float x) {
    union { float f; unsigned u; } v; v.f = x;
    unsigned u = v.u;
    return (ushort)((u + 0x7FFFu + ((u >> 16) & 1u)) >> 16);   // RNE
}

// ---------------- fused prologue: pack_mask + prep_w(heads) + prep_w(out) ----
__global__ __launch_bounds__(256) void k_prologue(const float* __restrict__ adj,
        unsigned* __restrict__ maskw,
        const float* __restrict__ W1, ushort* __restrict__ Wh1, ushort* __restrict__ Wl1,
        const float* __restrict__ W2, ushort* __restrict__ Wh2, ushort* __restrict__ Wl2) {
    int b = blockIdx.x, t = threadIdx.x;
    if (b < 2048) {
        int idx = b * 256 + t;                       // 4096*128 words
        int row = idx >> 7, w = idx & 127;
        const float4* ap = (const float4*)(adj + (size_t)row * N_NODES + w * 32);
        unsigned bits = 0;
#pragma unroll
        for (int q = 0; q < 8; ++q) {
            float4 v = ap[q];
            bits |= (v.x > 0.f ? 1u : 0u) << (q * 4 + 0);
            bits |= (v.y > 0.f ? 1u : 0u) << (q * 4 + 1);
            bits |= (v.z > 0.f ? 1u : 0u) << (q * 4 + 2);
            bits |= (v.w > 0.f ? 1u : 0u) << (q * 4 + 3);
        }
        maskw[idx] = bits;
    } else {
        const float* W; ushort *Wh, *Wl; int idx, kshift;
        if (b < 2560) { W = W1; Wh = Wh1; Wl = Wl1; idx = (b - 2048) * 256 + t; kshift = 8; }
        else          { W = W2; Wh = Wh2; Wl = Wl2; idx = (b - 2560) * 256 + t; kshift = 9; }
        int K = 1 << kshift;
        int n = idx & 63;
        int k = (idx >> 6) & (K - 1);
        int h = idx >> (6 + kshift);
        float v = W[idx];
        ushort hi = f2bf(v);
        union { unsigned u; float f; } hv; hv.u = ((unsigned)hi) << 16;
        ushort lo = f2bf(v - hv.f);
        size_t dst = ((size_t)h * 64 + n) * K + k;
        Wh[dst] = hi; Wl[dst] = lo;
    }
}

// ---------------- layer-1 H = X @ W (3-term split bf16 MFMA), 8-way K-split --
__global__ __launch_bounds__(512) void k_gemm_h(const float* __restrict__ X,
        const ushort* __restrict__ Wh, const ushort* __restrict__ Wl,
        const float* __restrict__ a,
        ushort* __restrict__ Ht, float* __restrict__ Rc,
        float* __restrict__ Tc, ushort* __restrict__ G2b, int K) {
    int head = blockIdx.y;
    int t = threadIdx.x, wave = t >> 6, lane = t & 63;
    int c = lane & 15, g = lane >> 4;
    int i0 = blockIdx.x * 16;
    int kq = K >> 3;
    int kbeg = wave * kq;
    const float* xrow = X + (size_t)(i0 + c) * K;
    f32x4 acc[4] = {};
    for (int k0 = kbeg; k0 < kbeg + kq; k0 += 32) {
        const float4* xp = (const float4*)(xrow + k0 + g * 8);
        float4 xa = xp[0], xb = xp[1];
        float xs[8] = {xa.x, xa.y, xa.z, xa.w, xb.x, xb.y, xb.z, xb.w};
        union { ushort s[8]; bf16x8 v; } ah, al;
#pragma unroll
        for (int e = 0; e < 8; ++e) {
            ushort hb = f2bf(xs[e]);
            ah.s[e] = hb;
            union { unsigned u; float f; } hv; hv.u = ((unsigned)hb) << 16;
            al.s[e] = f2bf(xs[e] - hv.f);
        }
#pragma unroll
        for (int nt = 0; nt < 4; ++nt) {
            size_t boff = ((size_t)head * 64 + nt * 16 + c) * K + k0 + g * 8;
            bf16x8 bh = *(const bf16x8*)(Wh + boff);
            bf16x8 bl = *(const bf16x8*)(Wl + boff);
            acc[nt] = __builtin_amdgcn_mfma_f32_16x16x32_bf16(ah.v, bh, acc[nt], 0, 0, 0);
            acc[nt] = __builtin_amdgcn_mfma_f32_16x16x32_bf16(al.v, bh, acc[nt], 0, 0, 0);
            acc[nt] = __builtin_amdgcn_mfma_f32_16x16x32_bf16(ah.v, bl, acc[nt], 0, 0, 0);
        }
    }
    __shared__ float red[8][64][17];
#pragma unroll
    for (int nt = 0; nt < 4; ++nt)
#pragma unroll
        for (int r = 0; r < 4; ++r)
            red[wave][lane][nt * 4 + r] = acc[nt][r];
    __syncthreads();
    if (wave != 0) return;
#pragma unroll
    for (int nt = 0; nt < 4; ++nt)
#pragma unroll
        for (int r = 0; r < 4; ++r) {
            float s = 0.f;
#pragma unroll
            for (int w = 0; w < 8; ++w) s += red[w][lane][nt * 4 + r];
            acc[nt][r] = s;
        }
    float a1v[4], a2v[4];
#pragma unroll
    for (int nt = 0; nt < 4; ++nt) {
        a1v[nt] = a[head * 128 + nt * 16 + c];
        a2v[nt] = a[head * 128 + 64 + nt * 16 + c];
    }
    float G2f[4];
#pragma unroll
    for (int r = 0; r < 4; ++r) {
        float f1 = 0.f, f2 = 0.f;
#pragma unroll
        for (int nt = 0; nt < 4; ++nt) {
            f1 = __builtin_fmaf(acc[nt][r], a1v[nt], f1);
            f2 = __builtin_fmaf(acc[nt][r], a2v[nt], f2);
        }
#pragma unroll
        for (int o = 1; o < 16; o <<= 1) {
            f1 += __shfl_xor(f1, o);
            f2 += __shfl_xor(f2, o);
        }
        float g2 = __builtin_amdgcn_exp2f(0.2f * LOG2E * f2);
        G2f[r] = g2;
        if (c == 0) {
            int i = i0 + g * 4 + r;
            Rc [head * N_NODES + i] = __builtin_amdgcn_exp2f(-0.8f * LOG2E * f1);
            Tc [head * N_NODES + i] = __builtin_amdgcn_exp2f( 0.8f * LOG2E * f2);
            G2b[head * N_NODES + i] = f2bf(g2);
        }
    }
#pragma unroll
    for (int nt = 0; nt < 4; ++nt) {
        union { ushort s[4]; bf16x4 v; } pk;
#pragma unroll
        for (int r = 0; r < 4; ++r) pk.s[r] = f2bf(acc[nt][r] * G2f[r]);
        *(bf16x4*)(Ht + ((size_t)head * 64 + nt * 16 + c) * N_NODES + i0 + g * 4) = pk.v;
    }
}

// ---------------- layer-2 GEMM with fused combine1 ---------------------------
__global__ __launch_bounds__(512) void k_gemm2(const float* __restrict__ accP,
        const float* __restrict__ Zp, int JS1,
        const ushort* __restrict__ Wh, const ushort* __restrict__ Wl,
        const float* __restrict__ a,
        ushort* __restrict__ Ht, float* __restrict__ Rc,
        float* __restrict__ Tc, ushort* __restrict__ G2b) {
    const int K = 512;
    int t = threadIdx.x, wave = t >> 6, lane = t & 63;
    int c = lane & 15, g = lane >> 4;
    int i0 = blockIdx.x * 16;
    int row = i0 + c;
    int hx = wave;
    float z = 0.f;
    for (int js = 0; js < JS1; ++js)
        z += Zp[(size_t)(hx * JS1 + js) * N_NODES + row];
    float rz = 1.0f / z;
    f32x4 acc[4] = {};
#pragma unroll
    for (int ki = 0; ki < 2; ++ki) {
        int k0 = wave * 64 + ki * 32;
        int n0 = ki * 32 + g * 8;
        float s[8] = {};
        for (int js = 0; js < JS1; ++js) {
            const float* apn = accP + ((size_t)(hx * JS1 + js) * N_NODES + row) * 64 + n0;
            float4 u0 = ((const float4*)apn)[0];
            float4 u1 = ((const float4*)apn)[1];
            s[0] += u0.x; s[1] += u0.y; s[2] += u0.z; s[3] += u0.w;
            s[4] += u1.x; s[5] += u1.y; s[6] += u1.z; s[7] += u1.w;
        }
        union { ushort sh[8]; bf16x8 v; } ah, al;
#pragma unroll
        for (int e = 0; e < 8; ++e) {
            float v = s[e] * rz;
            v = v > 0.f ? v : (__builtin_amdgcn_exp2f(v * LOG2E) - 1.f);   // elu
            ushort hb = f2bf(v);
            ah.sh[e] = hb;
            union { unsigned u; float f; } hv; hv.u = ((unsigned)hb) << 16;
            al.sh[e] = f2bf(v - hv.f);
        }
#pragma unroll
        for (int nt = 0; nt < 4; ++nt) {
            size_t boff = ((size_t)(nt * 16 + c)) * K + k0 + g * 8;
            bf16x8 bh = *(const bf16x8*)(Wh + boff);
            bf16x8 bl = *(const bf16x8*)(Wl + boff);
            acc[nt] = __builtin_amdgcn_mfma_f32_16x16x32_bf16(ah.v, bh, acc[nt], 0, 0, 0);
            acc[nt] = __builtin_amdgcn_mfma_f32_16x16x32_bf16(al.v, bh, acc[nt], 0, 0, 0);
            acc[nt] = __builtin_amdgcn_mfma_f32_16x16x32_bf16(ah.v, bl, acc[nt], 0, 0, 0);
        }
    }
    __shared__ float red[8][64][17];
#pragma unroll
    for (int nt = 0; nt < 4; ++nt)
#pragma unroll
        for (int r = 0; r < 4; ++r)
            red[wave][lane][nt * 4 + r] = acc[nt][r];
    __syncthreads();
    if (wave != 0) return;
#pragma unroll
    for (int nt = 0; nt < 4; ++nt)
#pragma unroll
        for (int r = 0; r < 4; ++r) {
            float s = 0.f;
#pragma unroll
            for (int w = 0; w < 8; ++w) s += red[w][lane][nt * 4 + r];
            acc[nt][r] = s;
        }
    float a1v[4], a2v[4];
#pragma unroll
    for (int nt = 0; nt < 4; ++nt) {
        a1v[nt] = a[nt * 16 + c];
        a2v[nt] = a[64 + nt * 16 + c];
    }
    float G2f[4];
#pragma unroll
    for (int r = 0; r < 4; ++r) {
        float f1 = 0.f, f2 = 0.f;
#pragma unroll
        for (int nt = 0; nt < 4; ++nt) {
            f1 = __builtin_fmaf(acc[nt][r], a1v[nt], f1);
            f2 = __builtin_fmaf(acc[nt][r], a2v[nt], f2);
        }
#pragma unroll
        for (int o = 1; o < 16; o <<= 1) {
            f1 += __shfl_xor(f1, o);
            f2 += __shfl_xor(f2, o);
        }
        float g2 = __builtin_amdgcn_exp2f(0.2f * LOG2E * f2);
        G2f[r] = g2;
        if (c == 0) {
            int i = i0 + g * 4 + r;
            Rc [i] = __builtin_amdgcn_exp2f(-0.8f * LOG2E * f1);
            Tc [i] = __builtin_amdgcn_exp2f( 0.8f * LOG2E * f2);
            G2b[i] = f2bf(g2);
        }
    }
#pragma unroll
    for (int nt = 0; nt < 4; ++nt) {
        union { ushort s[4]; bf16x4 v; } pk;
#pragma unroll
        for (int r = 0; r < 4; ++r) pk.s[r] = f2bf(acc[nt][r] * G2f[r]);
        *(bf16x4*)(Ht + ((size_t)(nt * 16 + c)) * N_NODES + i0 + g * 4) = pk.v;
    }
}

// ---------------- masked flash attention ------------------------------------
// 4 waves x 32 i-rows; mfma 32x32x16; factorized scores; z via third MFMA.
// NEW (R11): (1) tile-order ROTATION per block -- co-resident blocks start
// their j-sweep at different tiles, decorrelating barrier/stage phases across
// the 4 blocks sharing each CU (the ~100 cyc/slot idle was phase-aligned
// lgkm stalls). (2) balanced aux staging: mask rounds 2w,2w+1 on wave w (its
// own rows), T on waves 1/2, G2 on wave 3 -> per-wave loads 6/7/7/7.
__global__ __launch_bounds__(256)
__attribute__((amdgpu_waves_per_eu(4, 4)))
void k_attn(const ushort* __restrict__ Ht,
        const float* __restrict__ Rc, const float* __restrict__ Tc,
        const ushort* __restrict__ G2b, const unsigned* __restrict__ maskw,
        float* __restrict__ accP, float* __restrict__ Zp, int JS) {
    int rb = blockIdx.x, js = blockIdx.y, head = blockIdx.z;
    int t = threadIdx.x, wave = t >> 6, lane = t & 63;
    int r32 = lane & 31, half = lane >> 5;
    int i0b = rb * 128;
    int i0w = i0b + wave * 32;
    int irow = i0w + r32;
    int jcount = N_NODES / JS;
    int j0 = js * jcount;
    int ntiles = jcount / JT;
    int ntm1 = ntiles - 1;
    int rot = (rb + js * 3 + head * 5) & ntm1;
    const float R = Rc[head * N_NODES + irow];

    __shared__ ushort Hs[2][64 * JT];           // 2 x 16 KB, swizzled chunks
    __shared__ unsigned Ms[2][512];             // 2 x 2 KB: [128 rows][4 words]
    __shared__ float Ts[2][JT];                 // 2 x 512 B
    __shared__ ushort G2s[2][JT];               // 2 x 256 B

    int nH = (wave * 4) * 4 + (lane >> 4);      // row for s=0; +4 per s
    const ushort* gspH[4];
#pragma unroll
    for (int s = 0; s < 4; ++s) {
        int n = nH + s * 4;
        gspH[s] = Ht + ((size_t)head * 64 + n) * N_NODES + j0
                + (((lane & 15) ^ (n & 7)) << 3);
    }
    // balanced mask staging: wave w stages rounds 2w, 2w+1 (rows 32w..32w+31)
    const unsigned* msA = maskw + (size_t)(i0b + (2 * wave) * 16 + (lane >> 2)) * 128
                        + (j0 >> 5) + (lane & 3);
    const unsigned* msB = msA + (size_t)16 * 128;
    const float*  tsrcA = Tc  + (size_t)head * N_NODES + j0 + lane;        // wave 1
    const float*  tsrcB = Tc  + (size_t)head * N_NODES + j0 + 64 + lane;   // wave 2
    const ushort* gsrc  = G2b + (size_t)head * N_NODES + j0 + lane * 2;    // wave 3

    auto stage = [&](int b, int tile) {
        int go = tile * JT;
#pragma unroll
        for (int s = 0; s < 4; ++s)
            __builtin_amdgcn_global_load_lds((const unsigned*)(gspH[s] + go),
                    (unsigned*)&Hs[b][(wave * 4 + s) * 512], 16, 0, 0);
        __builtin_amdgcn_global_load_lds(msA + tile * 4,
                (unsigned*)&Ms[b][(2 * wave) * 64], 4, 0, 0);
        __builtin_amdgcn_global_load_lds(msB + tile * 4,
                (unsigned*)&Ms[b][(2 * wave + 1) * 64], 4, 0, 0);
        if (wave == 1)
            __builtin_amdgcn_global_load_lds((const unsigned*)(tsrcA + go),
                    (unsigned*)&Ts[b][0], 4, 0, 0);
        else if (wave == 2)
            __builtin_amdgcn_global_load_lds((const unsigned*)(tsrcB + go),
                    (unsigned*)&Ts[b][64], 4, 0, 0);
        else if (wave == 3)
            __builtin_amdgcn_global_load_lds((const unsigned*)(gsrc + go),
                    (unsigned*)&G2s[b][0], 4, 0, 0);
    };

    f32x16 acc0 = {}, acc1 = {}, acc2 = {};

    stage(0, rot);
    int buf = 0;
    for (int tt = 0; tt < ntiles; ++tt) {
        if (tt + 1 < ntiles) {
            stage(buf ^ 1, (tt + 1 + rot) & ntm1);
            if (wave == 0) asm volatile("s_waitcnt vmcnt(6)");
            else           asm volatile("s_waitcnt vmcnt(7)");
        } else {
            asm volatile("s_waitcnt vmcnt(0)");
        }
        __builtin_amdgcn_s_barrier();

        const char* hb = (const char*)&Hs[buf][0];
        union { uint4 v; unsigned w[4]; } mw;
        mw.v = *(const uint4*)&Ms[buf][(wave * 32 + r32) * 4];
#pragma unroll
        for (int itr = 0; itr < JT / 16; ++itr) {
            unsigned phys = (unsigned)(((itr * 2 + half) ^ (r32 & 7)) << 4);
            bf16x8 b0 = *(const bf16x8*)(hb + r32 * 256 + phys);
            bf16x8 b1 = *(const bf16x8*)(hb + (32 + r32) * 256 + phys);
            bf16x8 bg = *(const bf16x8*)(&G2s[buf][itr * 16 + half * 8]);
            unsigned mword = mw.w[itr >> 1];
            unsigned mshift = mword >> ((itr & 1) * 16 + half * 8);
            const float* tp = &Ts[buf][itr * 16 + half * 8];
            float4 ta = *(const float4*)tp;
            float4 tb = *(const float4*)(tp + 4);
            float tv[8] = {ta.x, ta.y, ta.z, ta.w, tb.x, tb.y, tb.z, tb.w};
            float p[8];
#pragma unroll
            for (int e = 0; e < 8; ++e) {
                int sm = (int)(mshift << (31 - e)) >> 31;        // bfe_i32 pattern
                float pe = fmaxf(tv[e], R);
                union { float f; int i; } pv; pv.f = pe;
                pv.i &= sm;
                p[e] = pv.f;
            }
            union { unsigned w[4]; bf16x8 v; } pa;
#pragma unroll
            for (int q = 0; q < 4; ++q)
                asm("v_cvt_pk_bf16_f32 %0, %1, %2"
                    : "=v"(pa.w[q]) : "v"(p[2 * q]), "v"(p[2 * q + 1]));
            acc0 = __builtin_amdgcn_mfma_f32_32x32x16_bf16(pa.v, b0, acc0, 0, 0, 0);
            acc1 = __builtin_amdgcn_mfma_f32_32x32x16_bf16(pa.v, b1, acc1, 0, 0, 0);
            acc2 = __builtin_amdgcn_mfma_f32_32x32x16_bf16(pa.v, bg, acc2, 0, 0, 0);
        }
        __builtin_amdgcn_s_barrier();
        buf ^= 1;
    }
    int slice = head * JS + js;
    if (r32 == 0) {
#pragma unroll
        for (int reg = 0; reg < 16; ++reg) {
            int drow = (reg & 3) + 8 * (reg >> 2) + 4 * half;
            Zp[(size_t)slice * N_NODES + i0w + drow] = acc2[reg];
        }
    }
    float* ap = accP + ((size_t)slice * N_NODES + i0w) * 64;
#pragma unroll
    for (int reg = 0; reg < 16; ++reg) {
        int drow = (reg & 3) + 8 * (reg >> 2) + 4 * half;
        ap[drow * 64 + r32] = acc0[reg];
        ap[drow * 64 + 32 + r32] = acc1[reg];
    }
}

// ---------------- combine partials (layer 2 / final output) ------------------
__global__ __launch_bounds__(256) void k_combine2(const float* __restrict__ accP,
        const float* __restrict__ Zp, float* __restrict__ out, int JS) {
    int idx = blockIdx.x * 256 + threadIdx.x;    // 4096*64
    int n = idx & 63, i = idx >> 6;
    float s = 0.f, z = 0.f;
    for (int j = 0; j < JS; ++j) {
        s += accP[((size_t)j * N_NODES + i) * 64 + n];
        z += Zp[(size_t)j * N_NODES + i];
    }
    out[idx] = s / z;
}

extern "C" void kernel_launch(void* const* d_in, const int* in_sizes, int n_in,
                              void* d_out, int out_size, void* d_ws, size_t ws_size,
                              hipStream_t stream) {
    const float* features = (const float*)d_in[0];
    const float* adj      = (const float*)d_in[1];
    const float* W_heads  = (const float*)d_in[2];
    const float* a_heads  = (const float*)d_in[3];
    const float* W_out    = (const float*)d_in[4];
    const float* a_out    = (const float*)d_in[5];
    float* out = (float*)d_out;

    int JS1, JS2;
    if (ws_size >= 43000000)      { JS1 = 4; JS2 = 32; }
    else if (ws_size >= 26000000) { JS1 = 2; JS2 = 16; }
    else                          { JS1 = 1; JS2 = 8;  }
    int slices = (8 * JS1 > JS2) ? 8 * JS1 : JS2;

    char* ws = (char*)d_ws;
    size_t off = 0;
    auto alloc = [&](size_t bytes) -> void* {
        void* p = ws + off; off = (off + bytes + 255) & ~(size_t)255; return p;
    };
    unsigned* maskw = (unsigned*)alloc((size_t)N_NODES * 128 * 4);
    ushort* Ht1 = (ushort*)alloc((size_t)8 * 64 * N_NODES * 2);   // n-major
    ushort* Ht2 = (ushort*)alloc((size_t)64 * N_NODES * 2);
    float* Rc1  = (float*)alloc((size_t)8 * N_NODES * 4);
    float* Tc1  = (float*)alloc((size_t)8 * N_NODES * 4);
    ushort* G2b1 = (ushort*)alloc((size_t)8 * N_NODES * 2);
    float* Rc2  = (float*)alloc((size_t)N_NODES * 4);
    float* Tc2  = (float*)alloc((size_t)N_NODES * 4);
    ushort* G2b2 = (ushort*)alloc((size_t)N_NODES * 2);
    ushort* Wh1 = (ushort*)alloc((size_t)8 * 64 * 256 * 2);
    ushort* Wl1 = (ushort*)alloc((size_t)8 * 64 * 256 * 2);
    ushort* Wh2 = (ushort*)alloc((size_t)64 * 512 * 2);
    ushort* Wl2 = (ushort*)alloc((size_t)64 * 512 * 2);
    float* accP = (float*)alloc((size_t)slices * N_NODES * 64 * 4);
    float* Zp   = (float*)alloc((size_t)slices * N_NODES * 4);

    hipLaunchKernelGGL(k_prologue, dim3(2688), dim3(256), 0, stream,
                       adj, maskw, W_heads, Wh1, Wl1, W_out, Wh2, Wl2);
    // layer 1
    hipLaunchKernelGGL(k_gemm_h, dim3(N_NODES / 16, 8), dim3(512), 0, stream,
                       features, Wh1, Wl1, a_heads, Ht1, Rc1, Tc1, G2b1, 256);
    hipLaunchKernelGGL(k_attn, dim3(32, JS1, 8), dim3(256), 0, stream,
                       Ht1, Rc1, Tc1, G2b1, maskw, accP, Zp, JS1);
    // layer 2 (combine1 fused into the GEMM)
    hipLaunchKernelGGL(k_gemm2, dim3(N_NODES / 16), dim3(512), 0, stream,
                       accP, Zp, JS1, Wh2, Wl2, a_out, Ht2, Rc2, Tc2, G2b2);
    hipLaunchKernelGGL(k_attn, dim3(32, JS2, 1), dim3(256), 0, stream,
                       Ht2, Rc2, Tc2, G2b2, maskw, accP, Zp, JS2);
    hipLaunchKernelGGL(k_combine2, dim3(N_NODES * 64 / 256), dim3(256), 0, stream,
                       accP, Zp, out, JS2);
}

// Round 12
// 115.320 us; speedup vs baseline: 1.7849x; 1.0515x over previous
//
#include <hip/hip_runtime.h>
#include <hip/hip_bf16.h>

#define N_NODES 4096
#define LOG2E 1.44269504088896340736f
#define JT 128                      // j-tile staged in LDS per block (dbuf)

typedef __attribute__((ext_vector_type(8))) short bf16x8;
typedef __attribute__((ext_vector_type(4))) short bf16x4;
typedef __attribute__((ext_vector_type(4))) float f32x4;
typedef __attribute__((ext_vector_type(16))) float f32x16;

static __device__ __forceinline__ ushort f2bf(float x) {
    union { float f; unsigned u; } v; v.f = x;
    unsigned u = v.u;
    return (ushort)((u + 0x7FFFu + ((u >> 16) & 1u)) >> 16);   // RNE
}
static __device__ __forceinline__ float bf2f(ushort h) {
    union { unsigned u; float f; } v; v.u = ((unsigned)h) << 16; return v.f;
}

// ---------------- fused prologue: pack_mask + prep_w(heads) + prep_w(out) ----
__global__ __launch_bounds__(256) void k_prologue(const float* __restrict__ adj,
        unsigned* __restrict__ maskw,
        const float* __restrict__ W1, ushort* __restrict__ Wh1, ushort* __restrict__ Wl1,
        const float* __restrict__ W2, ushort* __restrict__ Wh2, ushort* __restrict__ Wl2) {
    int b = blockIdx.x, t = threadIdx.x;
    if (b < 2048) {
        int idx = b * 256 + t;                       // 4096*128 words
        int row = idx >> 7, w = idx & 127;
        const float4* ap = (const float4*)(adj + (size_t)row * N_NODES + w * 32);
        unsigned bits = 0;
#pragma unroll
        for (int q = 0; q < 8; ++q) {
            float4 v = ap[q];
            bits |= (v.x > 0.f ? 1u : 0u) << (q * 4 + 0);
            bits |= (v.y > 0.f ? 1u : 0u) << (q * 4 + 1);
            bits |= (v.z > 0.f ? 1u : 0u) << (q * 4 + 2);
            bits |= (v.w > 0.f ? 1u : 0u) << (q * 4 + 3);
        }
        maskw[idx] = bits;
    } else {
        const float* W; ushort *Wh, *Wl; int idx, kshift;
        if (b < 2560) { W = W1; Wh = Wh1; Wl = Wl1; idx = (b - 2048) * 256 + t; kshift = 8; }
        else          { W = W2; Wh = Wh2; Wl = Wl2; idx = (b - 2560) * 256 + t; kshift = 9; }
        int K = 1 << kshift;
        int n = idx & 63;
        int k = (idx >> 6) & (K - 1);
        int h = idx >> (6 + kshift);
        float v = W[idx];
        ushort hi = f2bf(v);
        union { unsigned u; float f; } hv; hv.u = ((unsigned)hi) << 16;
        ushort lo = f2bf(v - hv.f);
        size_t dst = ((size_t)h * 64 + n) * K + k;
        Wh[dst] = hi; Wl[dst] = lo;
    }
}

// ---------------- layer-1 H = X @ W (3-term split bf16 MFMA), 8-way K-split --
__global__ __launch_bounds__(512) void k_gemm_h(const float* __restrict__ X,
        const ushort* __restrict__ Wh, const ushort* __restrict__ Wl,
        const float* __restrict__ a,
        ushort* __restrict__ Ht, float* __restrict__ Rc,
        float* __restrict__ Tc, ushort* __restrict__ G2b, int K) {
    int head = blockIdx.y;
    int t = threadIdx.x, wave = t >> 6, lane = t & 63;
    int c = lane & 15, g = lane >> 4;
    int i0 = blockIdx.x * 16;
    int kq = K >> 3;
    int kbeg = wave * kq;
    const float* xrow = X + (size_t)(i0 + c) * K;
    f32x4 acc[4] = {};
    for (int k0 = kbeg; k0 < kbeg + kq; k0 += 32) {
        const float4* xp = (const float4*)(xrow + k0 + g * 8);
        float4 xa = xp[0], xb = xp[1];
        float xs[8] = {xa.x, xa.y, xa.z, xa.w, xb.x, xb.y, xb.z, xb.w};
        union { ushort s[8]; bf16x8 v; } ah, al;
#pragma unroll
        for (int e = 0; e < 8; ++e) {
            ushort hb = f2bf(xs[e]);
            ah.s[e] = hb;
            union { unsigned u; float f; } hv; hv.u = ((unsigned)hb) << 16;
            al.s[e] = f2bf(xs[e] - hv.f);
        }
#pragma unroll
        for (int nt = 0; nt < 4; ++nt) {
            size_t boff = ((size_t)head * 64 + nt * 16 + c) * K + k0 + g * 8;
            bf16x8 bh = *(const bf16x8*)(Wh + boff);
            bf16x8 bl = *(const bf16x8*)(Wl + boff);
            acc[nt] = __builtin_amdgcn_mfma_f32_16x16x32_bf16(ah.v, bh, acc[nt], 0, 0, 0);
            acc[nt] = __builtin_amdgcn_mfma_f32_16x16x32_bf16(al.v, bh, acc[nt], 0, 0, 0);
            acc[nt] = __builtin_amdgcn_mfma_f32_16x16x32_bf16(ah.v, bl, acc[nt], 0, 0, 0);
        }
    }
    __shared__ float red[8][64][17];
#pragma unroll
    for (int nt = 0; nt < 4; ++nt)
#pragma unroll
        for (int r = 0; r < 4; ++r)
            red[wave][lane][nt * 4 + r] = acc[nt][r];
    __syncthreads();
    if (wave != 0) return;
#pragma unroll
    for (int nt = 0; nt < 4; ++nt)
#pragma unroll
        for (int r = 0; r < 4; ++r) {
            float s = 0.f;
#pragma unroll
            for (int w = 0; w < 8; ++w) s += red[w][lane][nt * 4 + r];
            acc[nt][r] = s;
        }
    float a1v[4], a2v[4];
#pragma unroll
    for (int nt = 0; nt < 4; ++nt) {
        a1v[nt] = a[head * 128 + nt * 16 + c];
        a2v[nt] = a[head * 128 + 64 + nt * 16 + c];
    }
    float G2f[4];
#pragma unroll
    for (int r = 0; r < 4; ++r) {
        float f1 = 0.f, f2 = 0.f;
#pragma unroll
        for (int nt = 0; nt < 4; ++nt) {
            f1 = __builtin_fmaf(acc[nt][r], a1v[nt], f1);
            f2 = __builtin_fmaf(acc[nt][r], a2v[nt], f2);
        }
#pragma unroll
        for (int o = 1; o < 16; o <<= 1) {
            f1 += __shfl_xor(f1, o);
            f2 += __shfl_xor(f2, o);
        }
        float g2 = __builtin_amdgcn_exp2f(0.2f * LOG2E * f2);
        G2f[r] = g2;
        if (c == 0) {
            int i = i0 + g * 4 + r;
            Rc [head * N_NODES + i] = __builtin_amdgcn_exp2f(-0.8f * LOG2E * f1);
            Tc [head * N_NODES + i] = __builtin_amdgcn_exp2f( 0.8f * LOG2E * f2);
            G2b[head * N_NODES + i] = f2bf(g2);
        }
    }
#pragma unroll
    for (int nt = 0; nt < 4; ++nt) {
        union { ushort s[4]; bf16x4 v; } pk;
#pragma unroll
        for (int r = 0; r < 4; ++r) pk.s[r] = f2bf(acc[nt][r] * G2f[r]);
        *(bf16x4*)(Ht + ((size_t)head * 64 + nt * 16 + c) * N_NODES + i0 + g * 4) = pk.v;
    }
}

// ---------------- layer-2 GEMM with fused combine1 (accP in bf16) ------------
__global__ __launch_bounds__(512) void k_gemm2(const ushort* __restrict__ accP,
        const float* __restrict__ Zp, int JS1,
        const ushort* __restrict__ Wh, const ushort* __restrict__ Wl,
        const float* __restrict__ a,
        ushort* __restrict__ Ht, float* __restrict__ Rc,
        float* __restrict__ Tc, ushort* __restrict__ G2b) {
    const int K = 512;
    int t = threadIdx.x, wave = t >> 6, lane = t & 63;
    int c = lane & 15, g = lane >> 4;
    int i0 = blockIdx.x * 16;
    int row = i0 + c;
    int hx = wave;
    float z = 0.f;
    for (int js = 0; js < JS1; ++js)
        z += Zp[(size_t)(hx * JS1 + js) * N_NODES + row];
    float rz = 1.0f / z;
    f32x4 acc[4] = {};
#pragma unroll
    for (int ki = 0; ki < 2; ++ki) {
        int k0 = wave * 64 + ki * 32;
        int n0 = ki * 32 + g * 8;
        float s[8] = {};
        for (int js = 0; js < JS1; ++js) {
            const ushort* apn = accP + ((size_t)(hx * JS1 + js) * N_NODES + row) * 64 + n0;
            union { int4 v; ushort u[8]; } uu;
            uu.v = *(const int4*)apn;
#pragma unroll
            for (int e = 0; e < 8; ++e) s[e] += bf2f(uu.u[e]);
        }
        union { ushort sh[8]; bf16x8 v; } ah, al;
#pragma unroll
        for (int e = 0; e < 8; ++e) {
            float v = s[e] * rz;
            v = v > 0.f ? v : (__builtin_amdgcn_exp2f(v * LOG2E) - 1.f);   // elu
            ushort hb = f2bf(v);
            ah.sh[e] = hb;
            union { unsigned u; float f; } hv; hv.u = ((unsigned)hb) << 16;
            al.sh[e] = f2bf(v - hv.f);
        }
#pragma unroll
        for (int nt = 0; nt < 4; ++nt) {
            size_t boff = ((size_t)(nt * 16 + c)) * K + k0 + g * 8;
            bf16x8 bh = *(const bf16x8*)(Wh + boff);
            bf16x8 bl = *(const bf16x8*)(Wl + boff);
            acc[nt] = __builtin_amdgcn_mfma_f32_16x16x32_bf16(ah.v, bh, acc[nt], 0, 0, 0);
            acc[nt] = __builtin_amdgcn_mfma_f32_16x16x32_bf16(al.v, bh, acc[nt], 0, 0, 0);
            acc[nt] = __builtin_amdgcn_mfma_f32_16x16x32_bf16(ah.v, bl, acc[nt], 0, 0, 0);
        }
    }
    __shared__ float red[8][64][17];
#pragma unroll
    for (int nt = 0; nt < 4; ++nt)
#pragma unroll
        for (int r = 0; r < 4; ++r)
            red[wave][lane][nt * 4 + r] = acc[nt][r];
    __syncthreads();
    if (wave != 0) return;
#pragma unroll
    for (int nt = 0; nt < 4; ++nt)
#pragma unroll
        for (int r = 0; r < 4; ++r) {
            float s = 0.f;
#pragma unroll
            for (int w = 0; w < 8; ++w) s += red[w][lane][nt * 4 + r];
            acc[nt][r] = s;
        }
    float a1v[4], a2v[4];
#pragma unroll
    for (int nt = 0; nt < 4; ++nt) {
        a1v[nt] = a[nt * 16 + c];
        a2v[nt] = a[64 + nt * 16 + c];
    }
    float G2f[4];
#pragma unroll
    for (int r = 0; r < 4; ++r) {
        float f1 = 0.f, f2 = 0.f;
#pragma unroll
        for (int nt = 0; nt < 4; ++nt) {
            f1 = __builtin_fmaf(acc[nt][r], a1v[nt], f1);
            f2 = __builtin_fmaf(acc[nt][r], a2v[nt], f2);
        }
#pragma unroll
        for (int o = 1; o < 16; o <<= 1) {
            f1 += __shfl_xor(f1, o);
            f2 += __shfl_xor(f2, o);
        }
        float g2 = __builtin_amdgcn_exp2f(0.2f * LOG2E * f2);
        G2f[r] = g2;
        if (c == 0) {
            int i = i0 + g * 4 + r;
            Rc [i] = __builtin_amdgcn_exp2f(-0.8f * LOG2E * f1);
            Tc [i] = __builtin_amdgcn_exp2f( 0.8f * LOG2E * f2);
            G2b[i] = f2bf(g2);
        }
    }
#pragma unroll
    for (int nt = 0; nt < 4; ++nt) {
        union { ushort s[4]; bf16x4 v; } pk;
#pragma unroll
        for (int r = 0; r < 4; ++r) pk.s[r] = f2bf(acc[nt][r] * G2f[r]);
        *(bf16x4*)(Ht + ((size_t)(nt * 16 + c)) * N_NODES + i0 + g * 4) = pk.v;
    }
}

// ---------------- masked flash attention ------------------------------------
// 4 waves x 32 i-rows; mfma 32x32x16; factorized scores; z via third MFMA.
// R12: accP stored bf16 -> slices=32 fits ws -> JS1=4/JS2=32 -> 1024 blocks
// = 4 blocks/CU = 4 waves/SIMD (R11 diagnosis: occupancy 27% == JS1=2 ==
// 2 waves/SIMD, latency-exposed; all prior in-loop surgery was fighting a
// TLP deficit). Rotation + balanced staging retained.
__global__ __launch_bounds__(256)
__attribute__((amdgpu_waves_per_eu(4, 4)))
void k_attn(const ushort* __restrict__ Ht,
        const float* __restrict__ Rc, const float* __restrict__ Tc,
        const ushort* __restrict__ G2b, const unsigned* __restrict__ maskw,
        ushort* __restrict__ accP, float* __restrict__ Zp, int JS) {
    int rb = blockIdx.x, js = blockIdx.y, head = blockIdx.z;
    int t = threadIdx.x, wave = t >> 6, lane = t & 63;
    int r32 = lane & 31, half = lane >> 5;
    int i0b = rb * 128;
    int i0w = i0b + wave * 32;
    int irow = i0w + r32;
    int jcount = N_NODES / JS;
    int j0 = js * jcount;
    int ntiles = jcount / JT;
    int ntm1 = ntiles - 1;
    int rot = (rb + js * 3 + head * 5) & ntm1;
    const float R = Rc[head * N_NODES + irow];

    __shared__ ushort Hs[2][64 * JT];           // 2 x 16 KB, swizzled chunks
    __shared__ unsigned Ms[2][512];             // 2 x 2 KB: [128 rows][4 words]
    __shared__ float Ts[2][JT];                 // 2 x 512 B
    __shared__ ushort G2s[2][JT];               // 2 x 256 B

    int nH = (wave * 4) * 4 + (lane >> 4);      // row for s=0; +4 per s
    const ushort* gspH[4];
#pragma unroll
    for (int s = 0; s < 4; ++s) {
        int n = nH + s * 4;
        gspH[s] = Ht + ((size_t)head * 64 + n) * N_NODES + j0
                + (((lane & 15) ^ (n & 7)) << 3);
    }
    const unsigned* msA = maskw + (size_t)(i0b + (2 * wave) * 16 + (lane >> 2)) * 128
                        + (j0 >> 5) + (lane & 3);
    const unsigned* msB = msA + (size_t)16 * 128;
    const float*  tsrcA = Tc  + (size_t)head * N_NODES + j0 + lane;        // wave 1
    const float*  tsrcB = Tc  + (size_t)head * N_NODES + j0 + 64 + lane;   // wave 2
    const ushort* gsrc  = G2b + (size_t)head * N_NODES + j0 + lane * 2;    // wave 3

    auto stage = [&](int b, int tile) {
        int go = tile * JT;
#pragma unroll
        for (int s = 0; s < 4; ++s)
            __builtin_amdgcn_global_load_lds((const unsigned*)(gspH[s] + go),
                    (unsigned*)&Hs[b][(wave * 4 + s) * 512], 16, 0, 0);
        __builtin_amdgcn_global_load_lds(msA + tile * 4,
                (unsigned*)&Ms[b][(2 * wave) * 64], 4, 0, 0);
        __builtin_amdgcn_global_load_lds(msB + tile * 4,
                (unsigned*)&Ms[b][(2 * wave + 1) * 64], 4, 0, 0);
        if (wave == 1)
            __builtin_amdgcn_global_load_lds((const unsigned*)(tsrcA + go),
                    (unsigned*)&Ts[b][0], 4, 0, 0);
        else if (wave == 2)
            __builtin_amdgcn_global_load_lds((const unsigned*)(tsrcB + go),
                    (unsigned*)&Ts[b][64], 4, 0, 0);
        else if (wave == 3)
            __builtin_amdgcn_global_load_lds((const unsigned*)(gsrc + go),
                    (unsigned*)&G2s[b][0], 4, 0, 0);
    };

    f32x16 acc0 = {}, acc1 = {}, acc2 = {};

    stage(0, rot);
    int buf = 0;
    for (int tt = 0; tt < ntiles; ++tt) {
        if (tt + 1 < ntiles) {
            stage(buf ^ 1, (tt + 1 + rot) & ntm1);
            if (wave == 0) asm volatile("s_waitcnt vmcnt(6)");
            else           asm volatile("s_waitcnt vmcnt(7)");
        } else {
            asm volatile("s_waitcnt vmcnt(0)");
        }
        __builtin_amdgcn_s_barrier();

        const char* hb = (const char*)&Hs[buf][0];
        union { uint4 v; unsigned w[4]; } mw;
        mw.v = *(const uint4*)&Ms[buf][(wave * 32 + r32) * 4];
#pragma unroll
        for (int itr = 0; itr < JT / 16; ++itr) {
            unsigned phys = (unsigned)(((itr * 2 + half) ^ (r32 & 7)) << 4);
            bf16x8 b0 = *(const bf16x8*)(hb + r32 * 256 + phys);
            bf16x8 b1 = *(const bf16x8*)(hb + (32 + r32) * 256 + phys);
            bf16x8 bg = *(const bf16x8*)(&G2s[buf][itr * 16 + half * 8]);
            unsigned mword = mw.w[itr >> 1];
            unsigned mshift = mword >> ((itr & 1) * 16 + half * 8);
            const float* tp = &Ts[buf][itr * 16 + half * 8];
            float4 ta = *(const float4*)tp;
            float4 tb = *(const float4*)(tp + 4);
            float tv[8] = {ta.x, ta.y, ta.z, ta.w, tb.x, tb.y, tb.z, tb.w};
            float p[8];
#pragma unroll
            for (int e = 0; e < 8; ++e) {
                int sm = (int)(mshift << (31 - e)) >> 31;        // bfe_i32 pattern
                float pe = fmaxf(tv[e], R);
                union { float f; int i; } pv; pv.f = pe;
                pv.i &= sm;
                p[e] = pv.f;
            }
            union { unsigned w[4]; bf16x8 v; } pa;
#pragma unroll
            for (int q = 0; q < 4; ++q)
                asm("v_cvt_pk_bf16_f32 %0, %1, %2"
                    : "=v"(pa.w[q]) : "v"(p[2 * q]), "v"(p[2 * q + 1]));
            acc0 = __builtin_amdgcn_mfma_f32_32x32x16_bf16(pa.v, b0, acc0, 0, 0, 0);
            acc1 = __builtin_amdgcn_mfma_f32_32x32x16_bf16(pa.v, b1, acc1, 0, 0, 0);
            acc2 = __builtin_amdgcn_mfma_f32_32x32x16_bf16(pa.v, bg, acc2, 0, 0, 0);
        }
        __builtin_amdgcn_s_barrier();
        buf ^= 1;
    }
    int slice = head * JS + js;
    if (r32 == 0) {
#pragma unroll
        for (int reg = 0; reg < 16; ++reg) {
            int drow = (reg & 3) + 8 * (reg >> 2) + 4 * half;
            Zp[(size_t)slice * N_NODES + i0w + drow] = acc2[reg];
        }
    }
    ushort* ap = accP + ((size_t)slice * N_NODES + i0w) * 64;
#pragma unroll
    for (int reg = 0; reg < 16; ++reg) {
        int drow = (reg & 3) + 8 * (reg >> 2) + 4 * half;
        ap[drow * 64 + r32] = f2bf(acc0[reg]);
        ap[drow * 64 + 32 + r32] = f2bf(acc1[reg]);
    }
}

// ---------------- combine partials (layer 2 / final output) ------------------
__global__ __launch_bounds__(256) void k_combine2(const ushort* __restrict__ accP,
        const float* __restrict__ Zp, float* __restrict__ out, int JS) {
    int idx = blockIdx.x * 256 + threadIdx.x;    // 4096*64
    int n = idx & 63, i = idx >> 6;
    float s = 0.f, z = 0.f;
    for (int j = 0; j < JS; ++j) {
        s += bf2f(accP[((size_t)j * N_NODES + i) * 64 + n]);
        z += Zp[(size_t)j * N_NODES + i];
    }
    out[idx] = s / z;
}

extern "C" void kernel_launch(void* const* d_in, const int* in_sizes, int n_in,
                              void* d_out, int out_size, void* d_ws, size_t ws_size,
                              hipStream_t stream) {
    const float* features = (const float*)d_in[0];
    const float* adj      = (const float*)d_in[1];
    const float* W_heads  = (const float*)d_in[2];
    const float* a_heads  = (const float*)d_in[3];
    const float* W_out    = (const float*)d_in[4];
    const float* a_out    = (const float*)d_in[5];
    float* out = (float*)d_out;

    // fixed ~7.6 MB; per-slice bf16 accP + f32 Zp ~0.55 MB
    int JS1, JS2;
    if (ws_size >= 26000000)      { JS1 = 4; JS2 = 32; }   // slices 32, 4 blk/CU
    else if (ws_size >= 17500000) { JS1 = 2; JS2 = 16; }
    else                          { JS1 = 1; JS2 = 8;  }
    int slices = (8 * JS1 > JS2) ? 8 * JS1 : JS2;

    char* ws = (char*)d_ws;
    size_t off = 0;
    auto alloc = [&](size_t bytes) -> void* {
        void* p = ws + off; off = (off + bytes + 255) & ~(size_t)255; return p;
    };
    unsigned* maskw = (unsigned*)alloc((size_t)N_NODES * 128 * 4);
    ushort* Ht1 = (ushort*)alloc((size_t)8 * 64 * N_NODES * 2);   // n-major
    ushort* Ht2 = (ushort*)alloc((size_t)64 * N_NODES * 2);
    float* Rc1  = (float*)alloc((size_t)8 * N_NODES * 4);
    float* Tc1  = (float*)alloc((size_t)8 * N_NODES * 4);
    ushort* G2b1 = (ushort*)alloc((size_t)8 * N_NODES * 2);
    float* Rc2  = (float*)alloc((size_t)N_NODES * 4);
    float* Tc2  = (float*)alloc((size_t)N_NODES * 4);
    ushort* G2b2 = (ushort*)alloc((size_t)N_NODES * 2);
    ushort* Wh1 = (ushort*)alloc((size_t)8 * 64 * 256 * 2);
    ushort* Wl1 = (ushort*)alloc((size_t)8 * 64 * 256 * 2);
    ushort* Wh2 = (ushort*)alloc((size_t)64 * 512 * 2);
    ushort* Wl2 = (ushort*)alloc((size_t)64 * 512 * 2);
    ushort* accP = (ushort*)alloc((size_t)slices * N_NODES * 64 * 2);
    float* Zp   = (float*)alloc((size_t)slices * N_NODES * 4);

    hipLaunchKernelGGL(k_prologue, dim3(2688), dim3(256), 0, stream,
                       adj, maskw, W_heads, Wh1, Wl1, W_out, Wh2, Wl2);
    // layer 1
    hipLaunchKernelGGL(k_gemm_h, dim3(N_NODES / 16, 8), dim3(512), 0, stream,
                       features, Wh1, Wl1, a_heads, Ht1, Rc1, Tc1, G2b1, 256);
    hipLaunchKernelGGL(k_attn, dim3(32, JS1, 8), dim3(256), 0, stream,
                       Ht1, Rc1, Tc1, G2b1, maskw, accP, Zp, JS1);
    // layer 2 (combine1 fused into the GEMM)
    hipLaunchKernelGGL(k_gemm2, dim3(N_NODES / 16), dim3(512), 0, stream,
                       accP, Zp, JS1, Wh2, Wl2, a_out, Ht2, Rc2, Tc2, G2b2);
    hipLaunchKernelGGL(k_attn, dim3(32, JS2, 1), dim3(256), 0, stream,
                       Ht2, Rc2, Tc2, G2b2, maskw, accP, Zp, JS2);
    hipLaunchKernelGGL(k_combine2, dim3(N_NODES * 64 / 256), dim3(256), 0, stream,
                       accP, Zp, out, JS2);
}